// Round 1
// baseline (929.922 us; speedup 1.0000x reference)
//
#include <hip/hip_runtime.h>

#define NN 20000
#define NP1 20001
#define DIM 256
#define NE 320000

// ---------------------------------------------------------------------------
// CSR build
// ---------------------------------------------------------------------------
__global__ __launch_bounds__(256) void zero_counts_kernel(int* counts, int n) {
    int i = blockIdx.x * 256 + threadIdx.x;
    if (i < n) counts[i] = 0;
}

// slots 0..3 -> relations {0,1,2,4}
__device__ __forceinline__ int slot_to_rel(int s) { return (s == 3) ? 4 : s; }

__global__ __launch_bounds__(256) void hist_kernel(const int* __restrict__ edges,
                                                   int* __restrict__ counts) {
    int s = blockIdx.y;
    int k = slot_to_rel(s);
    int e = blockIdx.x * 256 + threadIdx.x;
    if (e < NE) {
        int dst = edges[k * 2 * NE + NE + e];
        atomicAdd(&counts[s * NP1 + dst], 1);
    }
}

__global__ __launch_bounds__(256) void scan_kernel(const int* __restrict__ counts,
                                                   int* __restrict__ row_start,
                                                   int* __restrict__ cursor) {
    int s = blockIdx.x;
    const int* c = counts + s * NP1;
    int* rs = row_start + s * NP1;
    int* cur = cursor + s * NN;
    __shared__ int wsums[4];
    __shared__ int carry_s;
    if (threadIdx.x == 0) carry_s = 0;
    __syncthreads();
    int lane = threadIdx.x & 63, w = threadIdx.x >> 6;
    for (int base = 0; base < NN; base += 256) {
        int i = base + (int)threadIdx.x;
        int v = (i < NN) ? c[i] : 0;
        int x = v;
        #pragma unroll
        for (int off = 1; off < 64; off <<= 1) {
            int t = __shfl_up(x, off, 64);
            if (lane >= off) x += t;
        }
        if (lane == 63) wsums[w] = x;
        __syncthreads();
        int woff = 0;
        for (int j = 0; j < w; ++j) woff += wsums[j];
        int incl = x + woff;
        int excl = incl - v;
        int carry = carry_s;
        if (i < NN) { rs[i] = carry + excl; cur[i] = carry + excl; }
        __syncthreads();
        if (threadIdx.x == 255) carry_s = carry + incl;
        __syncthreads();
    }
    if (threadIdx.x == 0) rs[NN] = carry_s;
}

__global__ __launch_bounds__(256) void scatter_kernel(const int* __restrict__ edges,
                                                      int* __restrict__ cursor,
                                                      int* __restrict__ esorted) {
    int s = blockIdx.y;
    int k = slot_to_rel(s);
    int e = blockIdx.x * 256 + threadIdx.x;
    if (e < NE) {
        int src = edges[k * 2 * NE + e];
        int dst = edges[k * 2 * NE + NE + e];
        int pos = atomicAdd(&cursor[s * NN + dst], 1);
        esorted[s * NE + pos] = src;
    }
}

// ---------------------------------------------------------------------------
// Aggregation: one wave per dst row, float4 per lane (1KB coalesced per edge)
// ---------------------------------------------------------------------------
__global__ __launch_bounds__(256) void aggregate_l1_kernel(const float* __restrict__ x,
                                                           const int* __restrict__ row_start,
                                                           const int* __restrict__ esorted,
                                                           float* __restrict__ aggbase) {
    int s = blockIdx.y;                       // slot 0..3
    int srct = (s == 2) ? 1 : ((s == 3) ? 2 : 0);  // src node type of rel {0,1,2,4}
    const float* feat = x + (size_t)srct * NN * DIM;
    const int* rs = row_start + s * NP1;
    const int* es = esorted + s * NE;
    float* out = aggbase + (size_t)s * NN * DIM;

    int w = threadIdx.x >> 6, lane = threadIdx.x & 63;
    int row = blockIdx.x * 4 + w;
    if (row >= NN) return;
    int b = rs[row], e = rs[row + 1];
    float4 acc = make_float4(0.f, 0.f, 0.f, 0.f);
    for (int i = b; i < e; ++i) {
        int src = es[i];
        float4 v = *(const float4*)(feat + (size_t)src * DIM + lane * 4);
        acc.x += v.x; acc.y += v.y; acc.z += v.z; acc.w += v.w;
    }
    *(float4*)(out + (size_t)row * DIM + lane * 4) = acc;
}

__global__ __launch_bounds__(256) void aggregate_l2_kernel(const float* __restrict__ h0,
                                                           const float* __restrict__ h1,
                                                           const int* __restrict__ row_start,
                                                           const int* __restrict__ esorted,
                                                           float* __restrict__ aggbase) {
    int q = blockIdx.y;                 // 0: rel k0 (src h0), 1: rel k2 (src h1)
    int slot = q ? 2 : 0;
    const float* feat = q ? h1 : h0;
    const int* rs = row_start + slot * NP1;
    const int* es = esorted + slot * NE;
    float* out = aggbase + (size_t)slot * NN * DIM;

    int w = threadIdx.x >> 6, lane = threadIdx.x & 63;
    int row = blockIdx.x * 4 + w;
    if (row >= NN) return;
    int b = rs[row], e = rs[row + 1];
    float4 acc = make_float4(0.f, 0.f, 0.f, 0.f);
    for (int i = b; i < e; ++i) {
        int src = es[i];
        float4 v = *(const float4*)(feat + (size_t)src * DIM + lane * 4);
        acc.x += v.x; acc.y += v.y; acc.z += v.z; acc.w += v.w;
    }
    *(float4*)(out + (size_t)row * DIM + lane * 4) = acc;
}

// ---------------------------------------------------------------------------
// Build concatenated B matrices [768,256] and summed biases
// g=0: layer1 t0 (ka=0,kb=2, W1); g=1: layer1 t1 (ka=1,kb=4, W1); g=2: layer2 t0 (ka=0,kb=2, W2)
// ---------------------------------------------------------------------------
__global__ __launch_bounds__(256) void prep_B_kernel(const float* __restrict__ Wr1,
                                                     const float* __restrict__ br1,
                                                     const float* __restrict__ Wo1,
                                                     const float* __restrict__ Wr2,
                                                     const float* __restrict__ br2,
                                                     const float* __restrict__ Wo2,
                                                     float* __restrict__ Bcat,
                                                     float* __restrict__ biascat) {
    int g = blockIdx.y;
    int idx = blockIdx.x * 256 + threadIdx.x;   // 0 .. 768*256-1
    const float* Wr = (g == 2) ? Wr2 : Wr1;
    const float* Wo = (g == 2) ? Wo2 : Wo1;
    const float* br = (g == 2) ? br2 : br1;
    int ka = (g == 1) ? 1 : 0;
    int kb = (g == 1) ? 4 : 2;
    if (idx < 768 * DIM) {
        int r = idx >> 8, c = idx & 255;
        float v;
        if (r < 256)      v = Wr[(size_t)ka * 65536 + r * 256 + c];
        else if (r < 512) v = Wr[(size_t)kb * 65536 + (r - 256) * 256 + c];
        else              v = Wo[(size_t)ka * 65536 + (r - 512) * 256 + c] +
                              Wo[(size_t)kb * 65536 + (r - 512) * 256 + c];
        Bcat[(size_t)g * 768 * DIM + idx] = v;
        if (idx < DIM) biascat[g * DIM + idx] = br[ka * DIM + idx] + br[kb * DIM + idx];
    }
}

// ---------------------------------------------------------------------------
// fp32 GEMM: C[M,256] = [A0 | A1 | A2] (M x 768) @ B (768 x 256) + bias, opt relu
// Tiles: BM=64, BN=64, BK=16, 256 threads, 4x4 micro-tile
// ---------------------------------------------------------------------------
#define BM 64
#define BN 64
#define BK 16

__global__ __launch_bounds__(256) void gemm_cat3_kernel(const float* __restrict__ A0,
                                                        const float* __restrict__ A1,
                                                        const float* __restrict__ A2,
                                                        const float* __restrict__ B,
                                                        const float* __restrict__ bias,
                                                        float* __restrict__ C,
                                                        int M, int do_relu) {
    __shared__ float As[BK][BM + 4];   // padded: conflict-free, float4-aligned reads
    __shared__ float Bs[BK][BN];
    int tid = threadIdx.x;
    int tx = tid & 15, ty = tid >> 4;
    int row0 = blockIdx.x * BM;
    int col0 = blockIdx.y * BN;
    const float* Asrc[3] = {A0, A1, A2};

    float acc[4][4] = {};
    for (int kt = 0; kt < 768 / BK; ++kt) {
        int kbase = kt * BK;
        const float* Ap = Asrc[kbase >> 8];
        int klocal = kbase & 255;
        {   // A tile: 64 rows x 16 cols, one float4 per thread
            int r = tid >> 2;
            int c4 = (tid & 3) * 4;
            int row = row0 + r;
            float4 v = make_float4(0.f, 0.f, 0.f, 0.f);
            if (row < M) v = *(const float4*)(Ap + (size_t)row * DIM + klocal + c4);
            As[c4 + 0][r] = v.x; As[c4 + 1][r] = v.y;
            As[c4 + 2][r] = v.z; As[c4 + 3][r] = v.w;
        }
        {   // B tile: 16 rows x 64 cols, one float4 per thread
            int r = tid >> 4;
            int c4 = (tid & 15) * 4;
            float4 v = *(const float4*)(B + (size_t)(kbase + r) * DIM + col0 + c4);
            *(float4*)&Bs[r][c4] = v;
        }
        __syncthreads();
        #pragma unroll
        for (int kk = 0; kk < BK; ++kk) {
            float a[4], b[4];
            #pragma unroll
            for (int i = 0; i < 4; ++i) a[i] = As[kk][ty * 4 + i];
            #pragma unroll
            for (int j = 0; j < 4; ++j) b[j] = Bs[kk][tx * 4 + j];
            #pragma unroll
            for (int i = 0; i < 4; ++i)
                #pragma unroll
                for (int j = 0; j < 4; ++j)
                    acc[i][j] += a[i] * b[j];
        }
        __syncthreads();
    }
    #pragma unroll
    for (int i = 0; i < 4; ++i) {
        int row = row0 + ty * 4 + i;
        if (row < M) {
            #pragma unroll
            for (int j = 0; j < 4; ++j) {
                int col = col0 + tx * 4 + j;
                float v = acc[i][j] + bias[col];
                if (do_relu) v = fmaxf(v, 0.f);
                C[(size_t)row * DIM + col] = v;
            }
        }
    }
}

// ---------------------------------------------------------------------------
// Loss: wave per row logsumexp + gather y; then single-block mean
// ---------------------------------------------------------------------------
__global__ __launch_bounds__(256) void loss_rows_kernel(const float* __restrict__ logits,
                                                        const int* __restrict__ y,
                                                        float* __restrict__ nll) {
    int w = threadIdx.x >> 6, lane = threadIdx.x & 63;
    int row = blockIdx.x * 4 + w;
    if (row >= NN) return;
    float4 v = *(const float4*)(logits + (size_t)row * DIM + lane * 4);
    float m = fmaxf(fmaxf(v.x, v.y), fmaxf(v.z, v.w));
    #pragma unroll
    for (int off = 32; off; off >>= 1) m = fmaxf(m, __shfl_xor(m, off, 64));
    float s = __expf(v.x - m) + __expf(v.y - m) + __expf(v.z - m) + __expf(v.w - m);
    #pragma unroll
    for (int off = 32; off; off >>= 1) s += __shfl_xor(s, off, 64);
    float lse = m + __logf(s);
    int cls = y[row];
    int owner = cls >> 2;
    int sub = cls & 3;
    float pick = (sub & 2) ? ((sub & 1) ? v.w : v.z) : ((sub & 1) ? v.y : v.x);
    float ly = __shfl(pick, owner, 64);
    if (lane == 0) nll[row] = lse - ly;
}

__global__ __launch_bounds__(256) void reduce_mean_kernel(const float* __restrict__ nll,
                                                          float* __restrict__ out) {
    float s = 0.f;
    for (int i = threadIdx.x; i < NN; i += 256) s += nll[i];
    #pragma unroll
    for (int off = 32; off; off >>= 1) s += __shfl_xor(s, off, 64);
    __shared__ float ws_[4];
    int w = threadIdx.x >> 6, lane = threadIdx.x & 63;
    if (lane == 0) ws_[w] = s;
    __syncthreads();
    if (threadIdx.x == 0) out[0] = (ws_[0] + ws_[1] + ws_[2] + ws_[3]) / (float)NN;
}

// ---------------------------------------------------------------------------
extern "C" void kernel_launch(void* const* d_in, const int* in_sizes, int n_in,
                              void* d_out, int out_size, void* d_ws, size_t ws_size,
                              hipStream_t stream) {
    const float* x    = (const float*)d_in[0];
    const int*   edges= (const int*)d_in[1];
    const int*   y    = (const int*)d_in[2];
    const float* Wr1  = (const float*)d_in[3];
    const float* br1  = (const float*)d_in[4];
    const float* Wo1  = (const float*)d_in[5];
    const float* Wr2  = (const float*)d_in[6];
    const float* br2  = (const float*)d_in[7];
    const float* Wo2  = (const float*)d_in[8];
    float* out = (float*)d_out;

    char* ws = (char*)d_ws;
    size_t off = 0;
    auto alloc = [&](size_t bytes) {
        char* p = ws + off;
        off += (bytes + 511) & ~size_t(511);
        return p;
    };
    int*   counts   = (int*)  alloc(4 * NP1 * sizeof(int));
    int*   rowstart = (int*)  alloc(4 * NP1 * sizeof(int));
    int*   cursor   = (int*)  alloc(4 * NN * sizeof(int));
    int*   esorted  = (int*)  alloc(4 * (size_t)NE * sizeof(int));
    float* Bcat     = (float*)alloc(3 * 768 * (size_t)DIM * sizeof(float));
    float* biascat  = (float*)alloc(3 * DIM * sizeof(float));
    float* agg      = (float*)alloc(4 * (size_t)NN * DIM * sizeof(float));
    float* h0       = (float*)alloc((size_t)NN * DIM * sizeof(float));
    float* h1       = (float*)alloc((size_t)NN * DIM * sizeof(float));
    float* logits   = (float*)alloc((size_t)NN * DIM * sizeof(float));
    float* nll      = (float*)alloc(NN * sizeof(float));
    (void)in_sizes; (void)n_in; (void)out_size; (void)ws_size;

    const size_t ND = (size_t)NN * DIM;

    // 1. CSR build for relations {0,1,2,4}
    zero_counts_kernel<<<dim3((4 * NP1 + 255) / 256), 256, 0, stream>>>(counts, 4 * NP1);
    hist_kernel<<<dim3((NE + 255) / 256, 4), 256, 0, stream>>>(edges, counts);
    scan_kernel<<<dim3(4), 256, 0, stream>>>(counts, rowstart, cursor);
    scatter_kernel<<<dim3((NE + 255) / 256, 4), 256, 0, stream>>>(edges, cursor, esorted);

    // 2. Weight prep (3 fused [768,256] B matrices + biases)
    prep_B_kernel<<<dim3(768, 3), 256, 0, stream>>>(Wr1, br1, Wo1, Wr2, br2, Wo2, Bcat, biascat);

    // 3. Layer-1 aggregation (4 relations at once)
    aggregate_l1_kernel<<<dim3(NN / 4, 4), 256, 0, stream>>>(x, rowstart, esorted, agg);

    // 4. Layer-1 GEMMs (only t=0, t=1 needed downstream) + relu
    gemm_cat3_kernel<<<dim3((NN + BM - 1) / BM, DIM / BN), 256, 0, stream>>>(
        agg + 0 * ND, agg + 2 * ND, x + 0 * ND, Bcat + 0 * 768 * DIM, biascat + 0 * DIM,
        h0, NN, 1);
    gemm_cat3_kernel<<<dim3((NN + BM - 1) / BM, DIM / BN), 256, 0, stream>>>(
        agg + 1 * ND, agg + 3 * ND, x + 1 * ND, Bcat + 1 * 768 * DIM, biascat + 1 * DIM,
        h1, NN, 1);

    // 5. Layer-2 aggregation (rel k0 over h0 -> agg slot0, rel k2 over h1 -> agg slot2)
    aggregate_l2_kernel<<<dim3(NN / 4, 2), 256, 0, stream>>>(h0, h1, rowstart, esorted, agg);

    // 6. Layer-2 GEMM (t=0 only), no relu
    gemm_cat3_kernel<<<dim3((NN + BM - 1) / BM, DIM / BN), 256, 0, stream>>>(
        agg + 0 * ND, agg + 2 * ND, h0, Bcat + 2 * 768 * DIM, biascat + 2 * DIM,
        logits, NN, 0);

    // 7. Loss
    loss_rows_kernel<<<dim3(NN / 4), 256, 0, stream>>>(logits, y, nll);
    reduce_mean_kernel<<<dim3(1), 256, 0, stream>>>(nll, out);
}

// Round 2
// 611.128 us; speedup vs baseline: 1.5216x; 1.5216x over previous
//
#include <hip/hip_runtime.h>
#include <hip/hip_bf16.h>

#define NN 20000
#define NP1 20001
#define DIM 256
#define NE 320000

typedef __attribute__((ext_vector_type(8))) short short8v;   // 8 bf16 = 4 VGPRs
typedef __attribute__((ext_vector_type(4))) float float4v;
typedef __attribute__((ext_vector_type(8))) unsigned short ushort8v;

__device__ __forceinline__ unsigned short f2bf(float f) {
    unsigned int u = __float_as_uint(f);
    u += 0x7fffu + ((u >> 16) & 1u);          // round-to-nearest-even
    return (unsigned short)(u >> 16);
}
__device__ __forceinline__ float bflo(unsigned int u) {   // low bf16 of packed pair
    return __uint_as_float(u << 16);
}
__device__ __forceinline__ float bfhi(unsigned int u) {   // high bf16 of packed pair
    return __uint_as_float(u & 0xffff0000u);
}

// ---------------------------------------------------------------------------
// CSR build
// ---------------------------------------------------------------------------
__global__ __launch_bounds__(256) void zero_counts_kernel(int* counts, int n) {
    int i = blockIdx.x * 256 + threadIdx.x;
    if (i < n) counts[i] = 0;
}

// slots 0..3 -> relations {0,1,2,4}
__device__ __forceinline__ int slot_to_rel(int s) { return (s == 3) ? 4 : s; }

__global__ __launch_bounds__(256) void hist_kernel(const int* __restrict__ edges,
                                                   int* __restrict__ counts) {
    int s = blockIdx.y;
    int k = slot_to_rel(s);
    int e = blockIdx.x * 256 + threadIdx.x;
    if (e < NE) {
        int dst = edges[k * 2 * NE + NE + e];
        atomicAdd(&counts[s * NP1 + dst], 1);
    }
}

__global__ __launch_bounds__(256) void scan_kernel(const int* __restrict__ counts,
                                                   int* __restrict__ row_start,
                                                   int* __restrict__ cursor) {
    int s = blockIdx.x;
    const int* c = counts + s * NP1;
    int* rs = row_start + s * NP1;
    int* cur = cursor + s * NN;
    __shared__ int wsums[4];
    __shared__ int carry_s;
    if (threadIdx.x == 0) carry_s = 0;
    __syncthreads();
    int lane = threadIdx.x & 63, w = threadIdx.x >> 6;
    for (int base = 0; base < NN; base += 256) {
        int i = base + (int)threadIdx.x;
        int v = (i < NN) ? c[i] : 0;
        int x = v;
        #pragma unroll
        for (int off = 1; off < 64; off <<= 1) {
            int t = __shfl_up(x, off, 64);
            if (lane >= off) x += t;
        }
        if (lane == 63) wsums[w] = x;
        __syncthreads();
        int woff = 0;
        for (int j = 0; j < w; ++j) woff += wsums[j];
        int incl = x + woff;
        int excl = incl - v;
        int carry = carry_s;
        if (i < NN) { rs[i] = carry + excl; cur[i] = carry + excl; }
        __syncthreads();
        if (threadIdx.x == 255) carry_s = carry + incl;
        __syncthreads();
    }
    if (threadIdx.x == 0) rs[NN] = carry_s;
}

__global__ __launch_bounds__(256) void scatter_kernel(const int* __restrict__ edges,
                                                      int* __restrict__ cursor,
                                                      int* __restrict__ esorted) {
    int s = blockIdx.y;
    int k = slot_to_rel(s);
    int e = blockIdx.x * 256 + threadIdx.x;
    if (e < NE) {
        int src = edges[k * 2 * NE + e];
        int dst = edges[k * 2 * NE + NE + e];
        int pos = atomicAdd(&cursor[s * NN + dst], 1);
        esorted[s * NE + pos] = src;
    }
}

// ---------------------------------------------------------------------------
// x (fp32) -> bf16
// ---------------------------------------------------------------------------
__global__ __launch_bounds__(256) void conv_bf16_kernel(const float* __restrict__ x,
                                                        unsigned short* __restrict__ xb) {
    size_t i = ((size_t)blockIdx.x * 256 + threadIdx.x) * 4;   // 3*NN*DIM/4 threads
    float4 v = *(const float4*)(x + i);
    ushort4 o;
    o.x = f2bf(v.x); o.y = f2bf(v.y); o.z = f2bf(v.z); o.w = f2bf(v.w);
    *(ushort4*)(xb + i) = o;
}

// ---------------------------------------------------------------------------
// bf16 aggregation: wave per dst row, half-wave per edge (32 lanes x 16B = 512B row)
// fp32 accumulators, bf16 output.
// ---------------------------------------------------------------------------
__device__ __forceinline__ void agg_row(const unsigned short* feat, int b, int e,
                                        int lane, const int* es, unsigned short* outrow) {
    int half = lane >> 5, l = lane & 31;
    float acc[8] = {};
    for (int i = b + half; i < e; i += 2) {
        int src = es[i];
        uint4 raw = *(const uint4*)(feat + (size_t)src * DIM + l * 8);
        acc[0] += bflo(raw.x); acc[1] += bfhi(raw.x);
        acc[2] += bflo(raw.y); acc[3] += bfhi(raw.y);
        acc[4] += bflo(raw.z); acc[5] += bfhi(raw.z);
        acc[6] += bflo(raw.w); acc[7] += bfhi(raw.w);
    }
    #pragma unroll
    for (int j = 0; j < 8; ++j) acc[j] += __shfl_xor(acc[j], 32, 64);
    if (half == 0) {
        ushort8v o;
        #pragma unroll
        for (int j = 0; j < 8; ++j) o[j] = f2bf(acc[j]);
        *(ushort8v*)(outrow + l * 8) = o;
    }
}

__global__ __launch_bounds__(256) void aggregate_l1_kernel(const unsigned short* __restrict__ xb,
                                                           const int* __restrict__ row_start,
                                                           const int* __restrict__ esorted,
                                                           unsigned short* __restrict__ aggbase) {
    int s = blockIdx.y;                            // slot 0..3 = rel {0,1,2,4}
    int srct = (s == 2) ? 1 : ((s == 3) ? 2 : 0);  // src node type
    const unsigned short* feat = xb + (size_t)srct * NN * DIM;
    const int* rs = row_start + s * NP1;
    const int* es = esorted + s * NE;
    unsigned short* out = aggbase + (size_t)s * NN * DIM;
    int w = threadIdx.x >> 6, lane = threadIdx.x & 63;
    int row = blockIdx.x * 4 + w;
    if (row >= NN) return;
    agg_row(feat, rs[row], rs[row + 1], lane, es, out + (size_t)row * DIM);
}

__global__ __launch_bounds__(256) void aggregate_l2_kernel(const unsigned short* __restrict__ h0,
                                                           const unsigned short* __restrict__ h1,
                                                           const int* __restrict__ row_start,
                                                           const int* __restrict__ esorted,
                                                           unsigned short* __restrict__ aggbase) {
    int q = blockIdx.y;                 // 0: rel k0 (src h0) -> slot0; 1: rel k2 (src h1) -> slot2
    int slot = q ? 2 : 0;
    const unsigned short* feat = q ? h1 : h0;
    const int* rs = row_start + slot * NP1;
    const int* es = esorted + slot * NE;
    unsigned short* out = aggbase + (size_t)slot * NN * DIM;
    int w = threadIdx.x >> 6, lane = threadIdx.x & 63;
    int row = blockIdx.x * 4 + w;
    if (row >= NN) return;
    agg_row(feat, rs[row], rs[row + 1], lane, es, out + (size_t)row * DIM);
}

// ---------------------------------------------------------------------------
// Weight prep: BT[g][n][k] = Bcat[g][k][n] in bf16 (transposed for MFMA B frags),
// biascat fp32. g=0: L1-t0 (ka=0,kb=2,W1); g=1: L1-t1 (ka=1,kb=4,W1); g=2: L2-t0 (W2).
// ---------------------------------------------------------------------------
__global__ __launch_bounds__(256) void prep_BT_kernel(const float* __restrict__ Wr1,
                                                      const float* __restrict__ br1,
                                                      const float* __restrict__ Wo1,
                                                      const float* __restrict__ Wr2,
                                                      const float* __restrict__ br2,
                                                      const float* __restrict__ Wo2,
                                                      unsigned short* __restrict__ BT,
                                                      float* __restrict__ biascat) {
    int g = blockIdx.y;
    int n = blockIdx.x;                  // 0..255 output column
    const float* Wr = (g == 2) ? Wr2 : Wr1;
    const float* Wo = (g == 2) ? Wo2 : Wo1;
    const float* br = (g == 2) ? br2 : br1;
    int ka = (g == 1) ? 1 : 0;
    int kb = (g == 1) ? 4 : 2;
    for (int c = 0; c < 3; ++c) {
        int k = c * 256 + threadIdx.x;   // 0..767
        float v;
        if (k < 256)      v = Wr[(size_t)ka * 65536 + k * 256 + n];
        else if (k < 512) v = Wr[(size_t)kb * 65536 + (k - 256) * 256 + n];
        else              v = Wo[(size_t)ka * 65536 + (k - 512) * 256 + n] +
                              Wo[(size_t)kb * 65536 + (k - 512) * 256 + n];
        BT[(size_t)g * 768 * 256 + (size_t)n * 768 + k] = f2bf(v);
    }
    if (n == 0) biascat[g * DIM + threadIdx.x] =
        br[ka * DIM + threadIdx.x] + br[kb * DIM + threadIdx.x];
}

// ---------------------------------------------------------------------------
// MFMA bf16 GEMM, LDS-free: C[M,256] = [A0|A1|A2](M x 768) @ B(768x256) + bias.
// Block = 4 waves covering 128x128; wave = 64x64 (4x4 tiles of 16x16x32).
// Fragments gathered directly from global (L2/L3-resident); no barriers.
// ---------------------------------------------------------------------------
__global__ __launch_bounds__(256) void gemm_mfma_kernel(const unsigned short* __restrict__ A0,
                                                        const unsigned short* __restrict__ A1,
                                                        const unsigned short* __restrict__ A2,
                                                        const unsigned short* __restrict__ BT,
                                                        const float* __restrict__ bias,
                                                        unsigned short* __restrict__ Cb,  // bf16 out (or null)
                                                        float* __restrict__ Cf,           // fp32 out (or null)
                                                        int M, int relu) {
    int tid = threadIdx.x;
    int wave = tid >> 6, lane = tid & 63;
    int wr = wave >> 1, wc = wave & 1;
    int row0 = blockIdx.x * 128 + wr * 64;
    int col0 = blockIdx.y * 128 + wc * 64;
    int q = lane >> 4, r = lane & 15;            // quad / sub-lane

    const unsigned short* Asrc[3] = {A0, A1, A2};

    // Per-m-tile clamped A row offsets (elements); A frag: A[m=r][k = q*8 + j]
    size_t aoff[4];
    #pragma unroll
    for (int i = 0; i < 4; ++i) {
        int rowA = row0 + i * 16 + r;
        if (rowA > M - 1) rowA = M - 1;
        aoff[i] = (size_t)rowA * DIM + q * 8;
    }
    // Per-n-tile BT row pointers; B frag: B[k = q*8 + j][n = r]
    const unsigned short* bp[4];
    #pragma unroll
    for (int j = 0; j < 4; ++j)
        bp[j] = BT + (size_t)(col0 + j * 16 + r) * 768 + q * 8;

    float4v acc[4][4] = {};
    for (int seg = 0; seg < 3; ++seg) {
        const unsigned short* Ap = Asrc[seg];
        int kseg = seg * 256;
        #pragma unroll
        for (int kt = 0; kt < 8; ++kt) {
            int kl = kt * 32;
            short8v a[4], b[4];
            #pragma unroll
            for (int i = 0; i < 4; ++i)
                a[i] = *(const short8v*)(Ap + aoff[i] + kl);
            #pragma unroll
            for (int j = 0; j < 4; ++j)
                b[j] = *(const short8v*)(bp[j] + kseg + kl);
            #pragma unroll
            for (int i = 0; i < 4; ++i)
                #pragma unroll
                for (int j = 0; j < 4; ++j)
                    acc[i][j] = __builtin_amdgcn_mfma_f32_16x16x32_bf16(a[i], b[j], acc[i][j], 0, 0, 0);
        }
    }

    // Epilogue. C/D layout: col = r, row = q*4 + e  [guide-verified]
    float bj[4];
    #pragma unroll
    for (int j = 0; j < 4; ++j) bj[j] = bias[col0 + j * 16 + r];
    #pragma unroll
    for (int i = 0; i < 4; ++i) {
        int rowb = row0 + i * 16 + q * 4;
        #pragma unroll
        for (int e = 0; e < 4; ++e) {
            int rowc = rowb + e;
            if (rowc < M) {
                #pragma unroll
                for (int j = 0; j < 4; ++j) {
                    int col = col0 + j * 16 + r;
                    float v = acc[i][j][e] + bj[j];
                    if (relu) v = fmaxf(v, 0.f);
                    if (Cb) Cb[(size_t)rowc * DIM + col] = f2bf(v);
                    else    Cf[(size_t)rowc * DIM + col] = v;
                }
            }
        }
    }
}

// ---------------------------------------------------------------------------
// Loss: wave per row logsumexp + gather y; then single-block mean
// ---------------------------------------------------------------------------
__global__ __launch_bounds__(256) void loss_rows_kernel(const float* __restrict__ logits,
                                                        const int* __restrict__ y,
                                                        float* __restrict__ nll) {
    int w = threadIdx.x >> 6, lane = threadIdx.x & 63;
    int row = blockIdx.x * 4 + w;
    if (row >= NN) return;
    float4 v = *(const float4*)(logits + (size_t)row * DIM + lane * 4);
    float m = fmaxf(fmaxf(v.x, v.y), fmaxf(v.z, v.w));
    #pragma unroll
    for (int off = 32; off; off >>= 1) m = fmaxf(m, __shfl_xor(m, off, 64));
    float s = __expf(v.x - m) + __expf(v.y - m) + __expf(v.z - m) + __expf(v.w - m);
    #pragma unroll
    for (int off = 32; off; off >>= 1) s += __shfl_xor(s, off, 64);
    float lse = m + __logf(s);
    int cls = y[row];
    int owner = cls >> 2;
    int sub = cls & 3;
    float pick = (sub & 2) ? ((sub & 1) ? v.w : v.z) : ((sub & 1) ? v.y : v.x);
    float ly = __shfl(pick, owner, 64);
    if (lane == 0) nll[row] = lse - ly;
}

__global__ __launch_bounds__(256) void reduce_mean_kernel(const float* __restrict__ nll,
                                                          float* __restrict__ out) {
    float s = 0.f;
    for (int i = threadIdx.x; i < NN; i += 256) s += nll[i];
    #pragma unroll
    for (int off = 32; off; off >>= 1) s += __shfl_xor(s, off, 64);
    __shared__ float ws_[4];
    int w = threadIdx.x >> 6, lane = threadIdx.x & 63;
    if (lane == 0) ws_[w] = s;
    __syncthreads();
    if (threadIdx.x == 0) out[0] = (ws_[0] + ws_[1] + ws_[2] + ws_[3]) / (float)NN;
}

// ---------------------------------------------------------------------------
extern "C" void kernel_launch(void* const* d_in, const int* in_sizes, int n_in,
                              void* d_out, int out_size, void* d_ws, size_t ws_size,
                              hipStream_t stream) {
    const float* x    = (const float*)d_in[0];
    const int*   edges= (const int*)d_in[1];
    const int*   y    = (const int*)d_in[2];
    const float* Wr1  = (const float*)d_in[3];
    const float* br1  = (const float*)d_in[4];
    const float* Wo1  = (const float*)d_in[5];
    const float* Wr2  = (const float*)d_in[6];
    const float* br2  = (const float*)d_in[7];
    const float* Wo2  = (const float*)d_in[8];
    float* out = (float*)d_out;

    char* ws = (char*)d_ws;
    size_t off = 0;
    auto alloc = [&](size_t bytes) {
        char* p = ws + off;
        off += (bytes + 511) & ~size_t(511);
        return p;
    };
    int*   counts   = (int*)  alloc(4 * NP1 * sizeof(int));
    int*   rowstart = (int*)  alloc(4 * NP1 * sizeof(int));
    int*   cursor   = (int*)  alloc(4 * NN * sizeof(int));
    int*   esorted  = (int*)  alloc(4 * (size_t)NE * sizeof(int));
    unsigned short* BT      = (unsigned short*)alloc(3 * 768 * (size_t)DIM * 2);
    float*          biascat = (float*)         alloc(3 * DIM * sizeof(float));
    unsigned short* xb      = (unsigned short*)alloc(3 * (size_t)NN * DIM * 2);
    unsigned short* agg     = (unsigned short*)alloc(4 * (size_t)NN * DIM * 2);
    unsigned short* h0      = (unsigned short*)alloc((size_t)NN * DIM * 2);
    unsigned short* h1      = (unsigned short*)alloc((size_t)NN * DIM * 2);
    float*          logits  = (float*)         alloc((size_t)NN * DIM * sizeof(float));
    float*          nll     = (float*)         alloc(NN * sizeof(float));
    (void)in_sizes; (void)n_in; (void)out_size; (void)ws_size;

    const size_t ND = (size_t)NN * DIM;

    // 1. CSR build for relations {0,1,2,4}
    zero_counts_kernel<<<dim3((4 * NP1 + 255) / 256), 256, 0, stream>>>(counts, 4 * NP1);
    hist_kernel<<<dim3((NE + 255) / 256, 4), 256, 0, stream>>>(edges, counts);
    scan_kernel<<<dim3(4), 256, 0, stream>>>(counts, rowstart, cursor);
    scatter_kernel<<<dim3((NE + 255) / 256, 4), 256, 0, stream>>>(edges, cursor, esorted);

    // 2. x -> bf16; weight prep (transposed bf16 B matrices + fp32 biases)
    conv_bf16_kernel<<<dim3(3 * NN * DIM / 4 / 256), 256, 0, stream>>>(x, xb);
    prep_BT_kernel<<<dim3(256, 3), 256, 0, stream>>>(Wr1, br1, Wo1, Wr2, br2, Wo2, BT, biascat);

    // 3. Layer-1 aggregation (4 relations, bf16)
    aggregate_l1_kernel<<<dim3(NN / 4, 4), 256, 0, stream>>>(xb, rowstart, esorted, agg);

    // 4. Layer-1 MFMA GEMMs (t=0, t=1) + relu, bf16 out
    gemm_mfma_kernel<<<dim3((NN + 127) / 128, 2), 256, 0, stream>>>(
        agg + 0 * ND, agg + 2 * ND, xb + 0 * ND, BT + 0 * 768 * DIM, biascat + 0 * DIM,
        h0, nullptr, NN, 1);
    gemm_mfma_kernel<<<dim3((NN + 127) / 128, 2), 256, 0, stream>>>(
        agg + 1 * ND, agg + 3 * ND, xb + 1 * ND, BT + 1 * 768 * DIM, biascat + 1 * DIM,
        h1, nullptr, NN, 1);

    // 5. Layer-2 aggregation (rel k0 over h0 -> slot0, rel k2 over h1 -> slot2)
    aggregate_l2_kernel<<<dim3(NN / 4, 2), 256, 0, stream>>>(h0, h1, rowstart, esorted, agg);

    // 6. Layer-2 MFMA GEMM (t=0), fp32 logits out
    gemm_mfma_kernel<<<dim3((NN + 127) / 128, 2), 256, 0, stream>>>(
        agg + 0 * ND, agg + 2 * ND, h0, BT + 2 * 768 * DIM, biascat + 2 * DIM,
        nullptr, logits, NN, 0);

    // 7. Loss
    loss_rows_kernel<<<dim3(NN / 4), 256, 0, stream>>>(logits, y, nll);
    reduce_mean_kernel<<<dim3(1), 256, 0, stream>>>(nll, out);
}

// Round 3
// 470.479 us; speedup vs baseline: 1.9765x; 1.2989x over previous
//
#include <hip/hip_runtime.h>
#include <hip/hip_bf16.h>

#define NN 20000
#define NP1 20001
#define DIM 256
#define NE 320000
#define NB 79   // ceil(NN/256)

typedef __attribute__((ext_vector_type(8))) short short8v;   // 8 bf16 = 4 VGPRs
typedef __attribute__((ext_vector_type(4))) float float4v;
typedef __attribute__((ext_vector_type(8))) unsigned short ushort8v;

typedef __attribute__((address_space(3))) void lds_vp;
typedef const __attribute__((address_space(1))) void gbl_vp;

__device__ __forceinline__ unsigned short f2bf(float f) {
    unsigned int u = __float_as_uint(f);
    u += 0x7fffu + ((u >> 16) & 1u);          // round-to-nearest-even
    return (unsigned short)(u >> 16);
}
__device__ __forceinline__ float bflo(unsigned int u) { return __uint_as_float(u << 16); }
__device__ __forceinline__ float bfhi(unsigned int u) { return __uint_as_float(u & 0xffff0000u); }

// ---------------------------------------------------------------------------
// CSR build
// ---------------------------------------------------------------------------
__global__ __launch_bounds__(256) void zero_counts_kernel(int* counts, int n) {
    int i = blockIdx.x * 256 + threadIdx.x;
    if (i < n) counts[i] = 0;
}

__device__ __forceinline__ int slot_to_rel(int s) { return (s == 3) ? 4 : s; }

__global__ __launch_bounds__(256) void hist_kernel(const int* __restrict__ edges,
                                                   int* __restrict__ counts) {
    int s = blockIdx.y;
    int k = slot_to_rel(s);
    int e = blockIdx.x * 256 + threadIdx.x;
    if (e < NE) {
        int dst = edges[k * 2 * NE + NE + e];
        atomicAdd(&counts[s * NP1 + dst], 1);
    }
}

// Parallel scan: pass1 block-reduce, pass2 tiny scan of block sums, pass3 local scan+offset
__global__ __launch_bounds__(256) void scan_pass1_kernel(const int* __restrict__ counts,
                                                         int* __restrict__ blocksums) {
    int s = blockIdx.y, b = blockIdx.x;
    int i = b * 256 + threadIdx.x;
    int v = (i < NN) ? counts[s * NP1 + i] : 0;
    #pragma unroll
    for (int off = 32; off; off >>= 1) v += __shfl_xor(v, off, 64);
    __shared__ int w4[4];
    if ((threadIdx.x & 63) == 0) w4[threadIdx.x >> 6] = v;
    __syncthreads();
    if (threadIdx.x == 0) blocksums[s * NB + b] = w4[0] + w4[1] + w4[2] + w4[3];
}

__global__ __launch_bounds__(256) void scan_pass2_kernel(const int* __restrict__ blocksums,
                                                         int* __restrict__ blockoff,
                                                         int* __restrict__ row_start) {
    __shared__ int sb[4 * NB];
    for (int i = threadIdx.x; i < 4 * NB; i += 256) sb[i] = blocksums[i];
    __syncthreads();
    if (threadIdx.x < 4) {
        int s = threadIdx.x, run = 0;
        for (int j = 0; j < NB; ++j) {
            int t = sb[s * NB + j];
            blockoff[s * NB + j] = run;
            run += t;
        }
        row_start[s * NP1 + NN] = run;
    }
}

__global__ __launch_bounds__(256) void scan_pass3_kernel(const int* __restrict__ counts,
                                                         const int* __restrict__ blockoff,
                                                         int* __restrict__ row_start,
                                                         int* __restrict__ cursor) {
    int s = blockIdx.y, b = blockIdx.x;
    int i = b * 256 + threadIdx.x;
    int lane = threadIdx.x & 63, w = threadIdx.x >> 6;
    int v = (i < NN) ? counts[s * NP1 + i] : 0;
    int x = v;
    #pragma unroll
    for (int off = 1; off < 64; off <<= 1) {
        int t = __shfl_up(x, off, 64);
        if (lane >= off) x += t;
    }
    __shared__ int w4[4];
    if (lane == 63) w4[w] = x;
    __syncthreads();
    int woff = 0;
    for (int j = 0; j < w; ++j) woff += w4[j];
    int excl = x - v + woff + blockoff[s * NB + b];
    if (i < NN) {
        row_start[s * NP1 + i] = excl;
        cursor[s * NN + i] = excl;
    }
}

__global__ __launch_bounds__(256) void scatter_kernel(const int* __restrict__ edges,
                                                      int* __restrict__ cursor,
                                                      int* __restrict__ esorted) {
    int s = blockIdx.y;
    int k = slot_to_rel(s);
    int e = blockIdx.x * 256 + threadIdx.x;
    if (e < NE) {
        int src = edges[k * 2 * NE + e];
        int dst = edges[k * 2 * NE + NE + e];
        int pos = atomicAdd(&cursor[s * NN + dst], 1);
        esorted[s * NE + pos] = src;
    }
}

// ---------------------------------------------------------------------------
// x (fp32) -> bf16
// ---------------------------------------------------------------------------
__global__ __launch_bounds__(256) void conv_bf16_kernel(const float* __restrict__ x,
                                                        unsigned short* __restrict__ xb) {
    size_t i = ((size_t)blockIdx.x * 256 + threadIdx.x) * 4;
    float4 v = *(const float4*)(x + i);
    ushort4 o;
    o.x = f2bf(v.x); o.y = f2bf(v.y); o.z = f2bf(v.z); o.w = f2bf(v.w);
    *(ushort4*)(xb + i) = o;
}

// ---------------------------------------------------------------------------
// bf16 aggregation: wave per dst row, half-wave per edge
// ---------------------------------------------------------------------------
__device__ __forceinline__ void agg_row(const unsigned short* feat, int b, int e,
                                        int lane, const int* es, unsigned short* outrow) {
    int half = lane >> 5, l = lane & 31;
    float acc[8] = {};
    for (int i = b + half; i < e; i += 2) {
        int src = es[i];
        uint4 raw = *(const uint4*)(feat + (size_t)src * DIM + l * 8);
        acc[0] += bflo(raw.x); acc[1] += bfhi(raw.x);
        acc[2] += bflo(raw.y); acc[3] += bfhi(raw.y);
        acc[4] += bflo(raw.z); acc[5] += bfhi(raw.z);
        acc[6] += bflo(raw.w); acc[7] += bfhi(raw.w);
    }
    #pragma unroll
    for (int j = 0; j < 8; ++j) acc[j] += __shfl_xor(acc[j], 32, 64);
    if (half == 0) {
        ushort8v o;
        #pragma unroll
        for (int j = 0; j < 8; ++j) o[j] = f2bf(acc[j]);
        *(ushort8v*)(outrow + l * 8) = o;
    }
}

__global__ __launch_bounds__(256) void aggregate_l1_kernel(const unsigned short* __restrict__ xb,
                                                           const int* __restrict__ row_start,
                                                           const int* __restrict__ esorted,
                                                           unsigned short* __restrict__ aggbase) {
    int s = blockIdx.y;                            // slot 0..3 = rel {0,1,2,4}
    int srct = (s == 2) ? 1 : ((s == 3) ? 2 : 0);
    const unsigned short* feat = xb + (size_t)srct * NN * DIM;
    const int* rs = row_start + s * NP1;
    const int* es = esorted + s * NE;
    unsigned short* out = aggbase + (size_t)s * NN * DIM;
    int w = threadIdx.x >> 6, lane = threadIdx.x & 63;
    int row = blockIdx.x * 4 + w;
    if (row >= NN) return;
    agg_row(feat, rs[row], rs[row + 1], lane, es, out + (size_t)row * DIM);
}

__global__ __launch_bounds__(256) void aggregate_l2_kernel(const unsigned short* __restrict__ h0,
                                                           const unsigned short* __restrict__ h1,
                                                           const int* __restrict__ row_start,
                                                           const int* __restrict__ esorted,
                                                           unsigned short* __restrict__ aggbase) {
    int q = blockIdx.y;
    int slot = q ? 2 : 0;
    const unsigned short* feat = q ? h1 : h0;
    const int* rs = row_start + slot * NP1;
    const int* es = esorted + slot * NE;
    unsigned short* out = aggbase + (size_t)slot * NN * DIM;
    int w = threadIdx.x >> 6, lane = threadIdx.x & 63;
    int row = blockIdx.x * 4 + w;
    if (row >= NN) return;
    agg_row(feat, rs[row], rs[row + 1], lane, es, out + (size_t)row * DIM);
}

// ---------------------------------------------------------------------------
// Weight prep: BT[g][n][k], bf16; biascat fp32.
// ---------------------------------------------------------------------------
__global__ __launch_bounds__(256) void prep_BT_kernel(const float* __restrict__ Wr1,
                                                      const float* __restrict__ br1,
                                                      const float* __restrict__ Wo1,
                                                      const float* __restrict__ Wr2,
                                                      const float* __restrict__ br2,
                                                      const float* __restrict__ Wo2,
                                                      unsigned short* __restrict__ BT,
                                                      float* __restrict__ biascat) {
    int g = blockIdx.y;
    int n = blockIdx.x;
    const float* Wr = (g == 2) ? Wr2 : Wr1;
    const float* Wo = (g == 2) ? Wo2 : Wo1;
    const float* br = (g == 2) ? br2 : br1;
    int ka = (g == 1) ? 1 : 0;
    int kb = (g == 1) ? 4 : 2;
    for (int c = 0; c < 3; ++c) {
        int k = c * 256 + threadIdx.x;
        float v;
        if (k < 256)      v = Wr[(size_t)ka * 65536 + k * 256 + n];
        else if (k < 512) v = Wr[(size_t)kb * 65536 + (k - 256) * 256 + n];
        else              v = Wo[(size_t)ka * 65536 + (k - 512) * 256 + n] +
                              Wo[(size_t)kb * 65536 + (k - 512) * 256 + n];
        BT[(size_t)g * 768 * 256 + (size_t)n * 768 + k] = f2bf(v);
    }
    if (n == 0) biascat[g * DIM + threadIdx.x] =
        br[ka * DIM + threadIdx.x] + br[kb * DIM + threadIdx.x];
}

// ---------------------------------------------------------------------------
// MFMA bf16 GEMM, m97 structure: 128x128 block tile, BK=32, global_load_lds
// width-16 staging, 2-barrier K-loop, 16 MFMA/wave/step. blockIdx.z selects
// one of up to 2 fused GEMM problems.
// ---------------------------------------------------------------------------
struct GemmArgs {
    const unsigned short* A0[2];
    const unsigned short* A1[2];
    const unsigned short* A2[2];
    const unsigned short* BT[2];
    const float* bias[2];
    unsigned short* Cb[2];   // bf16 out (or null)
    float* Cf[2];            // fp32 out (or null)
    int relu;
    int M;
};

__global__ __launch_bounds__(256) void gemm_mfma_lds_kernel(GemmArgs ga) {
    __shared__ unsigned short Atile[128 * 32];
    __shared__ unsigned short Btile[128 * 32];
    int z = blockIdx.z;
    const unsigned short* Asrc[3] = {ga.A0[z], ga.A1[z], ga.A2[z]};
    const unsigned short* BT = ga.BT[z];
    int M = ga.M;

    int tid = threadIdx.x;
    int wave = tid >> 6, lane = tid & 63;
    int wr = wave >> 1, wc = wave & 1;
    int row0 = blockIdx.x * 128;
    int col0 = blockIdx.y * 128;
    int q = lane >> 4, r = lane & 15;

    // staging geometry: idx in [0,512): row = idx>>2, 16B chunk = idx&3
    int idx0 = tid, idx1 = 256 + tid;
    int arow0 = idx0 >> 2, arow1 = idx1 >> 2;
    int acol0 = (idx0 & 3) * 8, acol1 = (idx1 & 3) * 8;
    int ra0 = row0 + arow0; if (ra0 > M - 1) ra0 = M - 1;
    int ra1 = row0 + arow1; if (ra1 > M - 1) ra1 = M - 1;
    size_t aoff0 = (size_t)ra0 * DIM + acol0;
    size_t aoff1 = (size_t)ra1 * DIM + acol1;
    size_t boff0 = (size_t)(col0 + arow0) * 768 + acol0;
    size_t boff1 = (size_t)(col0 + arow1) * 768 + acol1;
    // wave-uniform LDS bases (lane writes base + lane*16)
    unsigned short* ldsA0 = &Atile[(size_t)(tid & ~63) * 8];
    unsigned short* ldsA1 = &Atile[2048 + (size_t)(tid & ~63) * 8];
    unsigned short* ldsB0 = &Btile[(size_t)(tid & ~63) * 8];
    unsigned short* ldsB1 = &Btile[2048 + (size_t)(tid & ~63) * 8];

    float4v acc[4][4] = {};
    #pragma unroll 1
    for (int seg = 0; seg < 3; ++seg) {
        const unsigned short* Ap = Asrc[seg];
        #pragma unroll 1
        for (int kt = 0; kt < 8; ++kt) {
            int kl = kt * 32;             // k offset within segment (A)
            int kb = seg * 256 + kl;      // global k offset (B)
            __builtin_amdgcn_global_load_lds((gbl_vp*)(Ap + aoff0 + kl), (lds_vp*)ldsA0, 16, 0, 0);
            __builtin_amdgcn_global_load_lds((gbl_vp*)(Ap + aoff1 + kl), (lds_vp*)ldsA1, 16, 0, 0);
            __builtin_amdgcn_global_load_lds((gbl_vp*)(BT + boff0 + kb), (lds_vp*)ldsB0, 16, 0, 0);
            __builtin_amdgcn_global_load_lds((gbl_vp*)(BT + boff1 + kb), (lds_vp*)ldsB1, 16, 0, 0);
            __syncthreads();
            short8v a[4], b[4];
            #pragma unroll
            for (int i = 0; i < 4; ++i)
                a[i] = *(const short8v*)&Atile[(size_t)(wr * 64 + i * 16 + r) * 32 + q * 8];
            #pragma unroll
            for (int j = 0; j < 4; ++j)
                b[j] = *(const short8v*)&Btile[(size_t)(wc * 64 + j * 16 + r) * 32 + q * 8];
            #pragma unroll
            for (int i = 0; i < 4; ++i)
                #pragma unroll
                for (int j = 0; j < 4; ++j)
                    acc[i][j] = __builtin_amdgcn_mfma_f32_16x16x32_bf16(a[i], b[j], acc[i][j], 0, 0, 0);
            __syncthreads();
        }
    }

    // Epilogue. C/D layout: col = r, row = q*4 + e
    unsigned short* Cb = ga.Cb[z];
    float* Cf = ga.Cf[z];
    int rowW0 = row0 + wr * 64;
    int colW0 = col0 + wc * 64;
    float bj[4];
    #pragma unroll
    for (int j = 0; j < 4; ++j) bj[j] = ga.bias[z][colW0 + j * 16 + r];
    #pragma unroll
    for (int i = 0; i < 4; ++i) {
        int rowb = rowW0 + i * 16 + q * 4;
        #pragma unroll
        for (int e = 0; e < 4; ++e) {
            int rowc = rowb + e;
            if (rowc < M) {
                #pragma unroll
                for (int j = 0; j < 4; ++j) {
                    int col = colW0 + j * 16 + r;
                    float v = acc[i][j][e] + bj[j];
                    if (ga.relu) v = fmaxf(v, 0.f);
                    if (Cb) Cb[(size_t)rowc * DIM + col] = f2bf(v);
                    else    Cf[(size_t)rowc * DIM + col] = v;
                }
            }
        }
    }
}

// ---------------------------------------------------------------------------
// Loss
// ---------------------------------------------------------------------------
__global__ __launch_bounds__(256) void loss_rows_kernel(const float* __restrict__ logits,
                                                        const int* __restrict__ y,
                                                        float* __restrict__ nll) {
    int w = threadIdx.x >> 6, lane = threadIdx.x & 63;
    int row = blockIdx.x * 4 + w;
    if (row >= NN) return;
    float4 v = *(const float4*)(logits + (size_t)row * DIM + lane * 4);
    float m = fmaxf(fmaxf(v.x, v.y), fmaxf(v.z, v.w));
    #pragma unroll
    for (int off = 32; off; off >>= 1) m = fmaxf(m, __shfl_xor(m, off, 64));
    float s = __expf(v.x - m) + __expf(v.y - m) + __expf(v.z - m) + __expf(v.w - m);
    #pragma unroll
    for (int off = 32; off; off >>= 1) s += __shfl_xor(s, off, 64);
    float lse = m + __logf(s);
    int cls = y[row];
    int owner = cls >> 2;
    int sub = cls & 3;
    float pick = (sub & 2) ? ((sub & 1) ? v.w : v.z) : ((sub & 1) ? v.y : v.x);
    float ly = __shfl(pick, owner, 64);
    if (lane == 0) nll[row] = lse - ly;
}

__global__ __launch_bounds__(256) void reduce_mean_kernel(const float* __restrict__ nll,
                                                          float* __restrict__ out) {
    float s = 0.f;
    for (int i = threadIdx.x; i < NN; i += 256) s += nll[i];
    #pragma unroll
    for (int off = 32; off; off >>= 1) s += __shfl_xor(s, off, 64);
    __shared__ float ws_[4];
    int w = threadIdx.x >> 6, lane = threadIdx.x & 63;
    if (lane == 0) ws_[w] = s;
    __syncthreads();
    if (threadIdx.x == 0) out[0] = (ws_[0] + ws_[1] + ws_[2] + ws_[3]) / (float)NN;
}

// ---------------------------------------------------------------------------
extern "C" void kernel_launch(void* const* d_in, const int* in_sizes, int n_in,
                              void* d_out, int out_size, void* d_ws, size_t ws_size,
                              hipStream_t stream) {
    const float* x    = (const float*)d_in[0];
    const int*   edges= (const int*)d_in[1];
    const int*   y    = (const int*)d_in[2];
    const float* Wr1  = (const float*)d_in[3];
    const float* br1  = (const float*)d_in[4];
    const float* Wo1  = (const float*)d_in[5];
    const float* Wr2  = (const float*)d_in[6];
    const float* br2  = (const float*)d_in[7];
    const float* Wo2  = (const float*)d_in[8];
    float* out = (float*)d_out;

    char* ws = (char*)d_ws;
    size_t off = 0;
    auto alloc = [&](size_t bytes) {
        char* p = ws + off;
        off += (bytes + 511) & ~size_t(511);
        return p;
    };
    int*   counts    = (int*)  alloc(4 * NP1 * sizeof(int));
    int*   rowstart  = (int*)  alloc(4 * NP1 * sizeof(int));
    int*   cursor    = (int*)  alloc(4 * NN * sizeof(int));
    int*   esorted   = (int*)  alloc(4 * (size_t)NE * sizeof(int));
    int*   blocksums = (int*)  alloc(4 * NB * sizeof(int));
    int*   blockoff  = (int*)  alloc(4 * NB * sizeof(int));
    unsigned short* BT      = (unsigned short*)alloc(3 * 768 * (size_t)DIM * 2);
    float*          biascat = (float*)         alloc(3 * DIM * sizeof(float));
    unsigned short* xb      = (unsigned short*)alloc(3 * (size_t)NN * DIM * 2);
    unsigned short* agg     = (unsigned short*)alloc(4 * (size_t)NN * DIM * 2);
    unsigned short* h0      = (unsigned short*)alloc((size_t)NN * DIM * 2);
    unsigned short* h1      = (unsigned short*)alloc((size_t)NN * DIM * 2);
    float*          logits  = (float*)         alloc((size_t)NN * DIM * sizeof(float));
    float*          nll     = (float*)         alloc(NN * sizeof(float));
    (void)in_sizes; (void)n_in; (void)out_size; (void)ws_size;

    const size_t ND = (size_t)NN * DIM;

    // 1. CSR build for relations {0,1,2,4}
    zero_counts_kernel<<<dim3((4 * NP1 + 255) / 256), 256, 0, stream>>>(counts, 4 * NP1);
    hist_kernel<<<dim3((NE + 255) / 256, 4), 256, 0, stream>>>(edges, counts);
    scan_pass1_kernel<<<dim3(NB, 4), 256, 0, stream>>>(counts, blocksums);
    scan_pass2_kernel<<<dim3(1), 256, 0, stream>>>(blocksums, blockoff, rowstart);
    scan_pass3_kernel<<<dim3(NB, 4), 256, 0, stream>>>(counts, blockoff, rowstart, cursor);
    scatter_kernel<<<dim3((NE + 255) / 256, 4), 256, 0, stream>>>(edges, cursor, esorted);

    // 2. x -> bf16; weight prep
    conv_bf16_kernel<<<dim3(3 * NN * DIM / 4 / 256), 256, 0, stream>>>(x, xb);
    prep_BT_kernel<<<dim3(256, 3), 256, 0, stream>>>(Wr1, br1, Wo1, Wr2, br2, Wo2, BT, biascat);

    // 3. Layer-1 aggregation (4 relations, bf16)
    aggregate_l1_kernel<<<dim3(NN / 4, 4), 256, 0, stream>>>(xb, rowstart, esorted, agg);

    // 4. Layer-1 MFMA GEMMs, both node types fused via blockIdx.z
    {
        GemmArgs ga;
        ga.A0[0] = agg + 0 * ND; ga.A1[0] = agg + 2 * ND; ga.A2[0] = xb + 0 * ND;
        ga.A0[1] = agg + 1 * ND; ga.A1[1] = agg + 3 * ND; ga.A2[1] = xb + 1 * ND;
        ga.BT[0] = BT + 0 * 768 * DIM; ga.BT[1] = BT + 1 * 768 * DIM;
        ga.bias[0] = biascat + 0 * DIM; ga.bias[1] = biascat + 1 * DIM;
        ga.Cb[0] = h0; ga.Cb[1] = h1;
        ga.Cf[0] = nullptr; ga.Cf[1] = nullptr;
        ga.relu = 1; ga.M = NN;
        gemm_mfma_lds_kernel<<<dim3((NN + 127) / 128, 2, 2), 256, 0, stream>>>(ga);
    }

    // 5. Layer-2 aggregation
    aggregate_l2_kernel<<<dim3(NN / 4, 2), 256, 0, stream>>>(h0, h1, rowstart, esorted, agg);

    // 6. Layer-2 MFMA GEMM (t=0), fp32 logits out
    {
        GemmArgs ga;
        ga.A0[0] = agg + 0 * ND; ga.A1[0] = agg + 2 * ND; ga.A2[0] = h0;
        ga.A0[1] = ga.A0[0]; ga.A1[1] = ga.A1[0]; ga.A2[1] = ga.A2[0];
        ga.BT[0] = BT + 2 * 768 * DIM; ga.BT[1] = ga.BT[0];
        ga.bias[0] = biascat + 2 * DIM; ga.bias[1] = ga.bias[0];
        ga.Cb[0] = nullptr; ga.Cb[1] = nullptr;
        ga.Cf[0] = logits; ga.Cf[1] = logits;
        ga.relu = 0; ga.M = NN;
        gemm_mfma_lds_kernel<<<dim3((NN + 127) / 128, 2, 1), 256, 0, stream>>>(ga);
    }

    // 7. Loss
    loss_rows_kernel<<<dim3(NN / 4), 256, 0, stream>>>(logits, y, nll);
    reduce_mean_kernel<<<dim3(1), 256, 0, stream>>>(nll, out);
}

// Round 4
// 423.310 us; speedup vs baseline: 2.1968x; 1.1114x over previous
//
#include <hip/hip_runtime.h>
#include <hip/hip_bf16.h>

#define NN 20000
#define NP1 20001
#define DIM 256
#define NE 320000
#define NB 79   // ceil(NN/256)

typedef __attribute__((ext_vector_type(8))) short short8v;   // 8 bf16 = 4 VGPRs
typedef __attribute__((ext_vector_type(4))) float float4v;
typedef __attribute__((ext_vector_type(2))) float float2v;
typedef __attribute__((ext_vector_type(8))) unsigned short ushort8v;

typedef __attribute__((address_space(3))) void lds_vp;
typedef const __attribute__((address_space(1))) void gbl_vp;

__device__ __forceinline__ unsigned short f2bf(float f) {
    unsigned int u = __float_as_uint(f);
    u += 0x7fffu + ((u >> 16) & 1u);          // round-to-nearest-even
    return (unsigned short)(u >> 16);
}
__device__ __forceinline__ unsigned char f2fp8(float f) {
    return (unsigned char)(__builtin_amdgcn_cvt_pk_fp8_f32(f, f, 0, 0) & 0xff);
}

// ---------------------------------------------------------------------------
// Fused setup: zero counts | x -> {bf16, fp8} | weight prep (BT bf16 + bias)
// ---------------------------------------------------------------------------
#define ZC_BLOCKS 313                      // ceil(4*NP1 / 256)
#define CONV_BLOCKS 7500                   // 3*NN*DIM / (256*8)
#define PREP_BLOCKS 768                    // 3 * 256

__global__ __launch_bounds__(256) void setup_kernel(const float* __restrict__ x,
                                                    const float* __restrict__ Wr1,
                                                    const float* __restrict__ br1,
                                                    const float* __restrict__ Wo1,
                                                    const float* __restrict__ Wr2,
                                                    const float* __restrict__ br2,
                                                    const float* __restrict__ Wo2,
                                                    int* __restrict__ counts,
                                                    unsigned short* __restrict__ xb,
                                                    unsigned char* __restrict__ xq,
                                                    unsigned short* __restrict__ BT,
                                                    float* __restrict__ biascat) {
    int b = blockIdx.x;
    if (b < ZC_BLOCKS) {
        int i = b * 256 + threadIdx.x;
        if (i < 4 * NP1) counts[i] = 0;
    } else if (b < ZC_BLOCKS + CONV_BLOCKS) {
        size_t i = ((size_t)(b - ZC_BLOCKS) * 256 + threadIdx.x) * 8;
        float4 v0 = *(const float4*)(x + i);
        float4 v1 = *(const float4*)(x + i + 4);
        if (i < 2 * (size_t)NN * DIM) {    // bf16 roots only needed for types 0,1
            ushort8v o;
            o[0] = f2bf(v0.x); o[1] = f2bf(v0.y); o[2] = f2bf(v0.z); o[3] = f2bf(v0.w);
            o[4] = f2bf(v1.x); o[5] = f2bf(v1.y); o[6] = f2bf(v1.z); o[7] = f2bf(v1.w);
            *(ushort8v*)(xb + i) = o;
        }
        unsigned int w0 = __builtin_amdgcn_cvt_pk_fp8_f32(v0.x, v0.y, 0, 0);
        w0 = __builtin_amdgcn_cvt_pk_fp8_f32(v0.z, v0.w, w0, 1);
        unsigned int w1 = __builtin_amdgcn_cvt_pk_fp8_f32(v1.x, v1.y, 0, 0);
        w1 = __builtin_amdgcn_cvt_pk_fp8_f32(v1.z, v1.w, w1, 1);
        *(uint2*)(xq + i) = make_uint2(w0, w1);
    } else {
        int pb = b - ZC_BLOCKS - CONV_BLOCKS;
        int g = pb >> 8, n = pb & 255;
        const float* Wr = (g == 2) ? Wr2 : Wr1;
        const float* Wo = (g == 2) ? Wo2 : Wo1;
        const float* br = (g == 2) ? br2 : br1;
        int ka = (g == 1) ? 1 : 0;
        int kb = (g == 1) ? 4 : 2;
        for (int c = 0; c < 3; ++c) {
            int k = c * 256 + threadIdx.x;
            float v;
            if (k < 256)      v = Wr[(size_t)ka * 65536 + k * 256 + n];
            else if (k < 512) v = Wr[(size_t)kb * 65536 + (k - 256) * 256 + n];
            else              v = Wo[(size_t)ka * 65536 + (k - 512) * 256 + n] +
                                  Wo[(size_t)kb * 65536 + (k - 512) * 256 + n];
            BT[(size_t)g * 768 * 256 + (size_t)n * 768 + k] = f2bf(v);
        }
        if (n == 0) biascat[g * DIM + threadIdx.x] =
            br[ka * DIM + threadIdx.x] + br[kb * DIM + threadIdx.x];
    }
}

// ---------------------------------------------------------------------------
// CSR build
// ---------------------------------------------------------------------------
__device__ __forceinline__ int slot_to_rel(int s) { return (s == 3) ? 4 : s; }

__global__ __launch_bounds__(256) void hist_kernel(const int* __restrict__ edges,
                                                   int* __restrict__ counts) {
    int s = blockIdx.y;
    int k = slot_to_rel(s);
    int e = blockIdx.x * 256 + threadIdx.x;
    if (e < NE) {
        int dst = edges[k * 2 * NE + NE + e];
        atomicAdd(&counts[s * NP1 + dst], 1);
    }
}

__global__ __launch_bounds__(256) void scan_pass1_kernel(const int* __restrict__ counts,
                                                         int* __restrict__ blocksums) {
    int s = blockIdx.y, b = blockIdx.x;
    int i = b * 256 + threadIdx.x;
    int v = (i < NN) ? counts[s * NP1 + i] : 0;
    #pragma unroll
    for (int off = 32; off; off >>= 1) v += __shfl_xor(v, off, 64);
    __shared__ int w4[4];
    if ((threadIdx.x & 63) == 0) w4[threadIdx.x >> 6] = v;
    __syncthreads();
    if (threadIdx.x == 0) blocksums[s * NB + b] = w4[0] + w4[1] + w4[2] + w4[3];
}

__global__ __launch_bounds__(256) void scan_pass2_kernel(const int* __restrict__ blocksums,
                                                         int* __restrict__ blockoff,
                                                         int* __restrict__ row_start) {
    __shared__ int sb[4 * NB];
    for (int i = threadIdx.x; i < 4 * NB; i += 256) sb[i] = blocksums[i];
    __syncthreads();
    if (threadIdx.x < 4) {
        int s = threadIdx.x, run = 0;
        for (int j = 0; j < NB; ++j) {
            int t = sb[s * NB + j];
            blockoff[s * NB + j] = run;
            run += t;
        }
        row_start[s * NP1 + NN] = run;
    }
}

__global__ __launch_bounds__(256) void scan_pass3_kernel(const int* __restrict__ counts,
                                                         const int* __restrict__ blockoff,
                                                         int* __restrict__ row_start,
                                                         int* __restrict__ cursor) {
    int s = blockIdx.y, b = blockIdx.x;
    int i = b * 256 + threadIdx.x;
    int lane = threadIdx.x & 63, w = threadIdx.x >> 6;
    int v = (i < NN) ? counts[s * NP1 + i] : 0;
    int x = v;
    #pragma unroll
    for (int off = 1; off < 64; off <<= 1) {
        int t = __shfl_up(x, off, 64);
        if (lane >= off) x += t;
    }
    __shared__ int w4[4];
    if (lane == 63) w4[w] = x;
    __syncthreads();
    int woff = 0;
    for (int j = 0; j < w; ++j) woff += w4[j];
    int excl = x - v + woff + blockoff[s * NB + b];
    if (i < NN) {
        row_start[s * NP1 + i] = excl;
        cursor[s * NN + i] = excl;
    }
}

__global__ __launch_bounds__(256) void scatter_kernel(const int* __restrict__ edges,
                                                      int* __restrict__ cursor,
                                                      int* __restrict__ esorted) {
    int s = blockIdx.y;
    int k = slot_to_rel(s);
    int e = blockIdx.x * 256 + threadIdx.x;
    if (e < NE) {
        int src = edges[k * 2 * NE + e];
        int dst = edges[k * 2 * NE + NE + e];
        int pos = atomicAdd(&cursor[s * NN + dst], 1);
        esorted[s * NE + pos] = src;
    }
}

// ---------------------------------------------------------------------------
// fp8 aggregation: wave per dst row, QUARTER-wave per edge (16 lanes x 16B =
// full 256B fp8 row) -> 4 edges in flight per wave. fp32 acc, bf16 out.
// ---------------------------------------------------------------------------
__device__ __forceinline__ void agg_row_fp8(const unsigned char* feat, int b, int e,
                                            int lane, const int* es,
                                            unsigned short* outrow) {
    int quad = lane >> 4, l = lane & 15;
    float acc[16] = {};
    for (int i = b + quad; i < e; i += 4) {
        int src = es[i];
        uint4 raw = *(const uint4*)(feat + (size_t)src * DIM + l * 16);
        float2v f;
        f = __builtin_amdgcn_cvt_pk_f32_fp8(raw.x, 0); acc[0]  += f.x; acc[1]  += f.y;
        f = __builtin_amdgcn_cvt_pk_f32_fp8(raw.x, 1); acc[2]  += f.x; acc[3]  += f.y;
        f = __builtin_amdgcn_cvt_pk_f32_fp8(raw.y, 0); acc[4]  += f.x; acc[5]  += f.y;
        f = __builtin_amdgcn_cvt_pk_f32_fp8(raw.y, 1); acc[6]  += f.x; acc[7]  += f.y;
        f = __builtin_amdgcn_cvt_pk_f32_fp8(raw.z, 0); acc[8]  += f.x; acc[9]  += f.y;
        f = __builtin_amdgcn_cvt_pk_f32_fp8(raw.z, 1); acc[10] += f.x; acc[11] += f.y;
        f = __builtin_amdgcn_cvt_pk_f32_fp8(raw.w, 0); acc[12] += f.x; acc[13] += f.y;
        f = __builtin_amdgcn_cvt_pk_f32_fp8(raw.w, 1); acc[14] += f.x; acc[15] += f.y;
    }
    #pragma unroll
    for (int j = 0; j < 16; ++j) {
        acc[j] += __shfl_xor(acc[j], 16, 64);
        acc[j] += __shfl_xor(acc[j], 32, 64);
    }
    if (quad == 0) {
        ushort8v o0, o1;
        #pragma unroll
        for (int j = 0; j < 8; ++j) { o0[j] = f2bf(acc[j]); o1[j] = f2bf(acc[8 + j]); }
        *(ushort8v*)(outrow + l * 16) = o0;
        *(ushort8v*)(outrow + l * 16 + 8) = o1;
    }
}

__global__ __launch_bounds__(256) void aggregate_l1_kernel(const unsigned char* __restrict__ xq,
                                                           const int* __restrict__ row_start,
                                                           const int* __restrict__ esorted,
                                                           unsigned short* __restrict__ aggbase) {
    int s = blockIdx.y;                            // slot 0..3 = rel {0,1,2,4}
    int srct = (s == 2) ? 1 : ((s == 3) ? 2 : 0);
    const unsigned char* feat = xq + (size_t)srct * NN * DIM;
    const int* rs = row_start + s * NP1;
    const int* es = esorted + s * NE;
    unsigned short* out = aggbase + (size_t)s * NN * DIM;
    int w = threadIdx.x >> 6, lane = threadIdx.x & 63;
    int row = blockIdx.x * 4 + w;
    if (row >= NN) return;
    agg_row_fp8(feat, rs[row], rs[row + 1], lane, es, out + (size_t)row * DIM);
}

__global__ __launch_bounds__(256) void aggregate_l2_kernel(const unsigned char* __restrict__ h0q,
                                                           const unsigned char* __restrict__ h1q,
                                                           const int* __restrict__ row_start,
                                                           const int* __restrict__ esorted,
                                                           unsigned short* __restrict__ aggbase) {
    int q = blockIdx.y;                 // 0: rel k0 (src h0) -> slot0; 1: rel k2 (src h1) -> slot2
    int slot = q ? 2 : 0;
    const unsigned char* feat = q ? h1q : h0q;
    const int* rs = row_start + slot * NP1;
    const int* es = esorted + slot * NE;
    unsigned short* out = aggbase + (size_t)slot * NN * DIM;
    int w = threadIdx.x >> 6, lane = threadIdx.x & 63;
    int row = blockIdx.x * 4 + w;
    if (row >= NN) return;
    agg_row_fp8(feat, rs[row], rs[row + 1], lane, es, out + (size_t)row * DIM);
}

// ---------------------------------------------------------------------------
// MFMA bf16 GEMM (m97 structure): 128x128 tile, BK=32, global_load_lds w=16.
// blockIdx.z selects one of up to 2 fused problems. Optional fp8 shadow out.
// ---------------------------------------------------------------------------
struct GemmArgs {
    const unsigned short* A0[2];
    const unsigned short* A1[2];
    const unsigned short* A2[2];
    const unsigned short* BT[2];
    const float* bias[2];
    unsigned short* Cb[2];   // bf16 out (or null)
    unsigned char* Cq[2];    // fp8 shadow out (or null)
    float* Cf[2];            // fp32 out (or null)
    int relu;
    int M;
};

__global__ __launch_bounds__(256) void gemm_mfma_lds_kernel(GemmArgs ga) {
    __shared__ unsigned short Atile[128 * 32];
    __shared__ unsigned short Btile[128 * 32];
    int z = blockIdx.z;
    const unsigned short* Asrc[3] = {ga.A0[z], ga.A1[z], ga.A2[z]};
    const unsigned short* BT = ga.BT[z];
    int M = ga.M;

    int tid = threadIdx.x;
    int wave = tid >> 6, lane = tid & 63;
    int wr = wave >> 1, wc = wave & 1;
    int row0 = blockIdx.x * 128;
    int col0 = blockIdx.y * 128;
    int q = lane >> 4, r = lane & 15;

    int idx0 = tid, idx1 = 256 + tid;
    int arow0 = idx0 >> 2, arow1 = idx1 >> 2;
    int acol0 = (idx0 & 3) * 8, acol1 = (idx1 & 3) * 8;
    int ra0 = row0 + arow0; if (ra0 > M - 1) ra0 = M - 1;
    int ra1 = row0 + arow1; if (ra1 > M - 1) ra1 = M - 1;
    size_t aoff0 = (size_t)ra0 * DIM + acol0;
    size_t aoff1 = (size_t)ra1 * DIM + acol1;
    size_t boff0 = (size_t)(col0 + arow0) * 768 + acol0;
    size_t boff1 = (size_t)(col0 + arow1) * 768 + acol1;
    unsigned short* ldsA0 = &Atile[(size_t)(tid & ~63) * 8];
    unsigned short* ldsA1 = &Atile[2048 + (size_t)(tid & ~63) * 8];
    unsigned short* ldsB0 = &Btile[(size_t)(tid & ~63) * 8];
    unsigned short* ldsB1 = &Btile[2048 + (size_t)(tid & ~63) * 8];

    float4v acc[4][4] = {};
    #pragma unroll 1
    for (int seg = 0; seg < 3; ++seg) {
        const unsigned short* Ap = Asrc[seg];
        #pragma unroll 1
        for (int kt = 0; kt < 8; ++kt) {
            int kl = kt * 32;
            int kb = seg * 256 + kl;
            __builtin_amdgcn_global_load_lds((gbl_vp*)(Ap + aoff0 + kl), (lds_vp*)ldsA0, 16, 0, 0);
            __builtin_amdgcn_global_load_lds((gbl_vp*)(Ap + aoff1 + kl), (lds_vp*)ldsA1, 16, 0, 0);
            __builtin_amdgcn_global_load_lds((gbl_vp*)(BT + boff0 + kb), (lds_vp*)ldsB0, 16, 0, 0);
            __builtin_amdgcn_global_load_lds((gbl_vp*)(BT + boff1 + kb), (lds_vp*)ldsB1, 16, 0, 0);
            __syncthreads();
            short8v a[4], b[4];
            #pragma unroll
            for (int i = 0; i < 4; ++i)
                a[i] = *(const short8v*)&Atile[(size_t)(wr * 64 + i * 16 + r) * 32 + q * 8];
            #pragma unroll
            for (int j = 0; j < 4; ++j)
                b[j] = *(const short8v*)&Btile[(size_t)(wc * 64 + j * 16 + r) * 32 + q * 8];
            #pragma unroll
            for (int i = 0; i < 4; ++i)
                #pragma unroll
                for (int j = 0; j < 4; ++j)
                    acc[i][j] = __builtin_amdgcn_mfma_f32_16x16x32_bf16(a[i], b[j], acc[i][j], 0, 0, 0);
            __syncthreads();
        }
    }

    // Epilogue. C/D layout: col = r, row = q*4 + e
    unsigned short* Cb = ga.Cb[z];
    unsigned char* Cq = ga.Cq[z];
    float* Cf = ga.Cf[z];
    int rowW0 = row0 + wr * 64;
    int colW0 = col0 + wc * 64;
    float bj[4];
    #pragma unroll
    for (int j = 0; j < 4; ++j) bj[j] = ga.bias[z][colW0 + j * 16 + r];
    #pragma unroll
    for (int i = 0; i < 4; ++i) {
        int rowb = rowW0 + i * 16 + q * 4;
        #pragma unroll
        for (int e = 0; e < 4; ++e) {
            int rowc = rowb + e;
            if (rowc < M) {
                #pragma unroll
                for (int j = 0; j < 4; ++j) {
                    int col = colW0 + j * 16 + r;
                    float v = acc[i][j][e] + bj[j];
                    if (ga.relu) v = fmaxf(v, 0.f);
                    if (Cb) {
                        Cb[(size_t)rowc * DIM + col] = f2bf(v);
                        if (Cq) Cq[(size_t)rowc * DIM + col] = f2fp8(v);
                    } else {
                        Cf[(size_t)rowc * DIM + col] = v;
                    }
                }
            }
        }
    }
}

// ---------------------------------------------------------------------------
// Loss
// ---------------------------------------------------------------------------
__global__ __launch_bounds__(256) void loss_rows_kernel(const float* __restrict__ logits,
                                                        const int* __restrict__ y,
                                                        float* __restrict__ nll) {
    int w = threadIdx.x >> 6, lane = threadIdx.x & 63;
    int row = blockIdx.x * 4 + w;
    if (row >= NN) return;
    float4 v = *(const float4*)(logits + (size_t)row * DIM + lane * 4);
    float m = fmaxf(fmaxf(v.x, v.y), fmaxf(v.z, v.w));
    #pragma unroll
    for (int off = 32; off; off >>= 1) m = fmaxf(m, __shfl_xor(m, off, 64));
    float s = __expf(v.x - m) + __expf(v.y - m) + __expf(v.z - m) + __expf(v.w - m);
    #pragma unroll
    for (int off = 32; off; off >>= 1) s += __shfl_xor(s, off, 64);
    float lse = m + __logf(s);
    int cls = y[row];
    int owner = cls >> 2;
    int sub = cls & 3;
    float pick = (sub & 2) ? ((sub & 1) ? v.w : v.z) : ((sub & 1) ? v.y : v.x);
    float ly = __shfl(pick, owner, 64);
    if (lane == 0) nll[row] = lse - ly;
}

__global__ __launch_bounds__(256) void reduce_mean_kernel(const float* __restrict__ nll,
                                                          float* __restrict__ out) {
    float s = 0.f;
    for (int i = threadIdx.x; i < NN; i += 256) s += nll[i];
    #pragma unroll
    for (int off = 32; off; off >>= 1) s += __shfl_xor(s, off, 64);
    __shared__ float ws_[4];
    int w = threadIdx.x >> 6, lane = threadIdx.x & 63;
    if (lane == 0) ws_[w] = s;
    __syncthreads();
    if (threadIdx.x == 0) out[0] = (ws_[0] + ws_[1] + ws_[2] + ws_[3]) / (float)NN;
}

// ---------------------------------------------------------------------------
extern "C" void kernel_launch(void* const* d_in, const int* in_sizes, int n_in,
                              void* d_out, int out_size, void* d_ws, size_t ws_size,
                              hipStream_t stream) {
    const float* x    = (const float*)d_in[0];
    const int*   edges= (const int*)d_in[1];
    const int*   y    = (const int*)d_in[2];
    const float* Wr1  = (const float*)d_in[3];
    const float* br1  = (const float*)d_in[4];
    const float* Wo1  = (const float*)d_in[5];
    const float* Wr2  = (const float*)d_in[6];
    const float* br2  = (const float*)d_in[7];
    const float* Wo2  = (const float*)d_in[8];
    float* out = (float*)d_out;

    char* ws = (char*)d_ws;
    size_t off = 0;
    auto alloc = [&](size_t bytes) {
        char* p = ws + off;
        off += (bytes + 511) & ~size_t(511);
        return p;
    };
    int*   counts    = (int*)  alloc(4 * NP1 * sizeof(int));
    int*   rowstart  = (int*)  alloc(4 * NP1 * sizeof(int));
    int*   cursor    = (int*)  alloc(4 * NN * sizeof(int));
    int*   esorted   = (int*)  alloc(4 * (size_t)NE * sizeof(int));
    int*   blocksums = (int*)  alloc(4 * NB * sizeof(int));
    int*   blockoff  = (int*)  alloc(4 * NB * sizeof(int));
    unsigned short* BT      = (unsigned short*)alloc(3 * 768 * (size_t)DIM * 2);
    float*          biascat = (float*)         alloc(3 * DIM * sizeof(float));
    unsigned short* xb      = (unsigned short*)alloc(2 * (size_t)NN * DIM * 2);
    unsigned char*  xq      = (unsigned char*) alloc(3 * (size_t)NN * DIM);
    unsigned short* agg     = (unsigned short*)alloc(4 * (size_t)NN * DIM * 2);
    unsigned short* h0      = (unsigned short*)alloc((size_t)NN * DIM * 2);
    unsigned short* h1      = (unsigned short*)alloc((size_t)NN * DIM * 2);
    unsigned char*  h0q     = (unsigned char*) alloc((size_t)NN * DIM);
    unsigned char*  h1q     = (unsigned char*) alloc((size_t)NN * DIM);
    float*          logits  = (float*)         alloc((size_t)NN * DIM * sizeof(float));
    float*          nll     = (float*)         alloc(NN * sizeof(float));
    (void)in_sizes; (void)n_in; (void)out_size; (void)ws_size;

    const size_t ND = (size_t)NN * DIM;

    // 1. Fused setup (zero counts | x->bf16/fp8 | weight prep)
    setup_kernel<<<dim3(ZC_BLOCKS + CONV_BLOCKS + PREP_BLOCKS), 256, 0, stream>>>(
        x, Wr1, br1, Wo1, Wr2, br2, Wo2, counts, xb, xq, BT, biascat);

    // 2. CSR build for relations {0,1,2,4}
    hist_kernel<<<dim3((NE + 255) / 256, 4), 256, 0, stream>>>(edges, counts);
    scan_pass1_kernel<<<dim3(NB, 4), 256, 0, stream>>>(counts, blocksums);
    scan_pass2_kernel<<<dim3(1), 256, 0, stream>>>(blocksums, blockoff, rowstart);
    scan_pass3_kernel<<<dim3(NB, 4), 256, 0, stream>>>(counts, blockoff, rowstart, cursor);
    scatter_kernel<<<dim3((NE + 255) / 256, 4), 256, 0, stream>>>(edges, cursor, esorted);

    // 3. Layer-1 aggregation (4 relations, fp8 gather -> bf16 agg)
    aggregate_l1_kernel<<<dim3(NN / 4, 4), 256, 0, stream>>>(xq, rowstart, esorted, agg);

    // 4. Layer-1 MFMA GEMMs, both node types fused via blockIdx.z; h bf16 + fp8
    {
        GemmArgs ga;
        ga.A0[0] = agg + 0 * ND; ga.A1[0] = agg + 2 * ND; ga.A2[0] = xb + 0 * ND;
        ga.A0[1] = agg + 1 * ND; ga.A1[1] = agg + 3 * ND; ga.A2[1] = xb + 1 * ND;
        ga.BT[0] = BT + 0 * 768 * DIM; ga.BT[1] = BT + 1 * 768 * DIM;
        ga.bias[0] = biascat + 0 * DIM; ga.bias[1] = biascat + 1 * DIM;
        ga.Cb[0] = h0; ga.Cb[1] = h1;
        ga.Cq[0] = h0q; ga.Cq[1] = h1q;
        ga.Cf[0] = nullptr; ga.Cf[1] = nullptr;
        ga.relu = 1; ga.M = NN;
        gemm_mfma_lds_kernel<<<dim3((NN + 127) / 128, 2, 2), 256, 0, stream>>>(ga);
    }

    // 5. Layer-2 aggregation (fp8 gather from h0q/h1q)
    aggregate_l2_kernel<<<dim3(NN / 4, 2), 256, 0, stream>>>(h0q, h1q, rowstart, esorted, agg);

    // 6. Layer-2 MFMA GEMM (t=0), fp32 logits out
    {
        GemmArgs ga;
        ga.A0[0] = agg + 0 * ND; ga.A1[0] = agg + 2 * ND; ga.A2[0] = h0;
        ga.A0[1] = ga.A0[0]; ga.A1[1] = ga.A1[0]; ga.A2[1] = ga.A2[0];
        ga.BT[0] = BT + 2 * 768 * DIM; ga.BT[1] = ga.BT[0];
        ga.bias[0] = biascat + 2 * DIM; ga.bias[1] = ga.bias[0];
        ga.Cb[0] = nullptr; ga.Cb[1] = nullptr;
        ga.Cq[0] = nullptr; ga.Cq[1] = nullptr;
        ga.Cf[0] = logits; ga.Cf[1] = logits;
        ga.relu = 0; ga.M = NN;
        gemm_mfma_lds_kernel<<<dim3((NN + 127) / 128, 2, 1), 256, 0, stream>>>(ga);
    }

    // 7. Loss
    loss_rows_kernel<<<dim3(NN / 4), 256, 0, stream>>>(logits, y, nll);
    reduce_mean_kernel<<<dim3(1), 256, 0, stream>>>(nll, out);
}

// Round 5
// 332.280 us; speedup vs baseline: 2.7986x; 1.2740x over previous
//
#include <hip/hip_runtime.h>
#include <hip/hip_bf16.h>

#define NN 20000
#define NP1 20001
#define DIM 256
#define NE 320000

#define NBKT 79        // buckets of 256 dst rows (last bucket = 32 rows)
#define BROWS 256
#define ACH 4096       // edges per phase-A block
#define ABLK 79        // ceil(NE/ACH)
#define STAGE_CAP 6144 // avg bucket = 4096, sigma 64; 6144 = +32 sigma

typedef __attribute__((ext_vector_type(8))) short short8v;   // 8 bf16 = 4 VGPRs
typedef __attribute__((ext_vector_type(4))) float float4v;
typedef __attribute__((ext_vector_type(2))) float float2v;
typedef __attribute__((ext_vector_type(8))) unsigned short ushort8v;

typedef __attribute__((address_space(3))) void lds_vp;
typedef const __attribute__((address_space(1))) void gbl_vp;

__device__ __forceinline__ unsigned short f2bf(float f) {
    unsigned int u = __float_as_uint(f);
    u += 0x7fffu + ((u >> 16) & 1u);          // round-to-nearest-even
    return (unsigned short)(u >> 16);
}
__device__ __forceinline__ unsigned char f2fp8(float f) {
    return (unsigned char)(__builtin_amdgcn_cvt_pk_fp8_f32(f, f, 0, 0) & 0xff);
}

__device__ __forceinline__ int slot_to_rel(int s) { return (s == 3) ? 4 : s; }

// ---------------------------------------------------------------------------
// Fused setup: zero bucket_counts | x -> {bf16, fp8} | weight prep
// ---------------------------------------------------------------------------
#define ZB_BLOCKS 2                        // zero 4*NBKT bucket counters
#define CONV_BLOCKS 7500                   // 3*NN*DIM / (256*8)
#define PREP_BLOCKS 768                    // 3 * 256

__global__ __launch_bounds__(256) void setup_kernel(const float* __restrict__ x,
                                                    const float* __restrict__ Wr1,
                                                    const float* __restrict__ br1,
                                                    const float* __restrict__ Wo1,
                                                    const float* __restrict__ Wr2,
                                                    const float* __restrict__ br2,
                                                    const float* __restrict__ Wo2,
                                                    int* __restrict__ bucket_counts,
                                                    unsigned short* __restrict__ xb,
                                                    unsigned char* __restrict__ xq,
                                                    unsigned short* __restrict__ BT,
                                                    float* __restrict__ biascat) {
    int b = blockIdx.x;
    if (b < ZB_BLOCKS) {
        int i = b * 256 + threadIdx.x;
        if (i < 4 * NBKT) bucket_counts[i] = 0;
    } else if (b < ZB_BLOCKS + CONV_BLOCKS) {
        size_t i = ((size_t)(b - ZB_BLOCKS) * 256 + threadIdx.x) * 8;
        float4 v0 = *(const float4*)(x + i);
        float4 v1 = *(const float4*)(x + i + 4);
        if (i < 2 * (size_t)NN * DIM) {    // bf16 roots only needed for types 0,1
            ushort8v o;
            o[0] = f2bf(v0.x); o[1] = f2bf(v0.y); o[2] = f2bf(v0.z); o[3] = f2bf(v0.w);
            o[4] = f2bf(v1.x); o[5] = f2bf(v1.y); o[6] = f2bf(v1.z); o[7] = f2bf(v1.w);
            *(ushort8v*)(xb + i) = o;
        }
        unsigned int w0 = __builtin_amdgcn_cvt_pk_fp8_f32(v0.x, v0.y, 0, 0);
        w0 = __builtin_amdgcn_cvt_pk_fp8_f32(v0.z, v0.w, w0, 1);
        unsigned int w1 = __builtin_amdgcn_cvt_pk_fp8_f32(v1.x, v1.y, 0, 0);
        w1 = __builtin_amdgcn_cvt_pk_fp8_f32(v1.z, v1.w, w1, 1);
        *(uint2*)(xq + i) = make_uint2(w0, w1);
    } else {
        int pb = b - ZB_BLOCKS - CONV_BLOCKS;
        int g = pb >> 8, n = pb & 255;
        const float* Wr = (g == 2) ? Wr2 : Wr1;
        const float* Wo = (g == 2) ? Wo2 : Wo1;
        const float* br = (g == 2) ? br2 : br1;
        int ka = (g == 1) ? 1 : 0;
        int kb = (g == 1) ? 4 : 2;
        for (int c = 0; c < 3; ++c) {
            int k = c * 256 + threadIdx.x;
            float v;
            if (k < 256)      v = Wr[(size_t)ka * 65536 + k * 256 + n];
            else if (k < 512) v = Wr[(size_t)kb * 65536 + (k - 256) * 256 + n];
            else              v = Wo[(size_t)ka * 65536 + (k - 512) * 256 + n] +
                                  Wo[(size_t)kb * 65536 + (k - 512) * 256 + n];
            BT[(size_t)g * 768 * 256 + (size_t)n * 768 + k] = f2bf(v);
        }
        if (n == 0) biascat[g * DIM + threadIdx.x] =
            br[ka * DIM + threadIdx.x] + br[kb * DIM + threadIdx.x];
    }
}

// ---------------------------------------------------------------------------
// Phase A1: per-block LDS bucket histogram -> few global atomics
// ---------------------------------------------------------------------------
__global__ __launch_bounds__(256) void binA_count_kernel(const int* __restrict__ edges,
                                                         int* __restrict__ bucket_counts) {
    int s = blockIdx.y, k = slot_to_rel(s);
    __shared__ int cnt[NBKT];
    for (int t = threadIdx.x; t < NBKT; t += 256) cnt[t] = 0;
    __syncthreads();
    int e0 = blockIdx.x * ACH;
    #pragma unroll
    for (int j = 0; j < 16; ++j) {
        int e = e0 + j * 256 + threadIdx.x;
        if (e < NE) atomicAdd(&cnt[edges[k * 2 * NE + NE + e] >> 8], 1);
    }
    __syncthreads();
    for (int t = threadIdx.x; t < NBKT; t += 256)
        if (cnt[t]) atomicAdd(&bucket_counts[s * NBKT + t], cnt[t]);
}

// ---------------------------------------------------------------------------
// Bucket scan (tiny): exclusive scan of 79 buckets per slot
// ---------------------------------------------------------------------------
__global__ __launch_bounds__(64) void bucket_scan_kernel(const int* __restrict__ bucket_counts,
                                                         int* __restrict__ bucket_start,
                                                         int* __restrict__ bucket_cursor) {
    int t = threadIdx.x;
    if (t < 4) {
        int run = 0;
        for (int b = 0; b < NBKT; ++b) {
            bucket_start[t * (NBKT + 1) + b] = run;
            bucket_cursor[t * NBKT + b] = run;
            run += bucket_counts[t * NBKT + b];
        }
        bucket_start[t * (NBKT + 1) + NBKT] = run;  // == NE
    }
}

// ---------------------------------------------------------------------------
// Phase A2: LDS-staged binning -> pairs grouped bucket-major, coalesced writes
// ---------------------------------------------------------------------------
__global__ __launch_bounds__(256) void binA_scatter_kernel(const int* __restrict__ edges,
                                                           int* __restrict__ bucket_cursor,
                                                           uint2* __restrict__ pairs) {
    int s = blockIdx.y, k = slot_to_rel(s);
    __shared__ int cnt[NBKT], scn[NBKT], cur[NBKT], gb[NBKT];
    __shared__ uint2 st[ACH];
    for (int t = threadIdx.x; t < NBKT; t += 256) cnt[t] = 0;
    __syncthreads();
    int e0 = blockIdx.x * ACH;
    #pragma unroll
    for (int j = 0; j < 16; ++j) {
        int e = e0 + j * 256 + threadIdx.x;
        if (e < NE) atomicAdd(&cnt[edges[k * 2 * NE + NE + e] >> 8], 1);
    }
    __syncthreads();
    if (threadIdx.x == 0) {
        int run = 0;
        for (int b = 0; b < NBKT; ++b) { scn[b] = run; run += cnt[b]; }
    }
    __syncthreads();
    for (int t = threadIdx.x; t < NBKT; t += 256) {
        cur[t] = scn[t];
        gb[t] = atomicAdd(&bucket_cursor[s * NBKT + t], cnt[t]) - scn[t];
    }
    __syncthreads();
    #pragma unroll
    for (int j = 0; j < 16; ++j) {
        int e = e0 + j * 256 + threadIdx.x;
        if (e < NE) {
            unsigned int src = edges[k * 2 * NE + e];
            unsigned int dst = edges[k * 2 * NE + NE + e];
            int slot = atomicAdd(&cur[dst >> 8], 1);
            st[slot] = make_uint2(src, dst);
        }
    }
    __syncthreads();
    int nthis = NE - e0; if (nthis > ACH) nthis = ACH;
    for (int i = threadIdx.x; i < nthis; i += 256) {
        uint2 p = st[i];
        pairs[(size_t)s * NE + gb[p.y >> 8] + i] = p;
    }
}

// ---------------------------------------------------------------------------
// Phase B: per (slot,bucket) block — per-row counts + scan in LDS (produces
// row_start), LDS-atomic scatter into staging, coalesced esorted write.
// ---------------------------------------------------------------------------
__global__ __launch_bounds__(256) void binB_kernel(const uint2* __restrict__ pairs,
                                                   const int* __restrict__ bucket_start,
                                                   int* __restrict__ row_start,
                                                   int* __restrict__ esorted) {
    int s = blockIdx.y, b = blockIdx.x;
    int base = bucket_start[s * (NBKT + 1) + b];
    int end  = bucket_start[s * (NBKT + 1) + b + 1];
    int n = end - base;
    int row0 = b * BROWS;
    int nrows = NN - row0; if (nrows > BROWS) nrows = BROWS;

    __shared__ int rcnt[BROWS];
    __shared__ int rcur[BROWS];
    __shared__ int stg[STAGE_CAP];
    __shared__ int w4[4];
    rcnt[threadIdx.x] = 0;
    __syncthreads();
    for (int i = threadIdx.x; i < n; i += 256) {
        uint2 p = pairs[(size_t)s * NE + base + i];
        atomicAdd(&rcnt[p.y & 255], 1);
    }
    __syncthreads();
    // exclusive block scan of rcnt[256]
    int lane = threadIdx.x & 63, w = threadIdx.x >> 6;
    int v = rcnt[threadIdx.x];
    int x = v;
    #pragma unroll
    for (int off = 1; off < 64; off <<= 1) {
        int t = __shfl_up(x, off, 64);
        if (lane >= off) x += t;
    }
    if (lane == 63) w4[w] = x;
    __syncthreads();
    int woff = 0;
    for (int j = 0; j < w; ++j) woff += w4[j];
    int excl = x - v + woff;
    if (threadIdx.x < nrows) row_start[s * NP1 + row0 + threadIdx.x] = base + excl;
    if (b == NBKT - 1 && threadIdx.x == 0) row_start[s * NP1 + NN] = end;
    rcur[threadIdx.x] = excl;
    __syncthreads();

    if (n <= STAGE_CAP) {
        for (int i = threadIdx.x; i < n; i += 256) {
            uint2 p = pairs[(size_t)s * NE + base + i];
            int pos = atomicAdd(&rcur[p.y & 255], 1);
            stg[pos] = (int)p.x;
        }
        __syncthreads();
        for (int i = threadIdx.x; i < n; i += 256)
            esorted[(size_t)s * NE + base + i] = stg[i];
    } else {  // pathological fallback (never triggered for this data)
        for (int i = threadIdx.x; i < n; i += 256) {
            uint2 p = pairs[(size_t)s * NE + base + i];
            int pos = atomicAdd(&rcur[p.y & 255], 1);
            esorted[(size_t)s * NE + base + pos] = (int)p.x;
        }
    }
}

// ---------------------------------------------------------------------------
// fp8 aggregation: wave per dst row, QUARTER-wave per edge (16 lanes x 16B =
// full 256B fp8 row) -> 4 edges in flight per wave. fp32 acc, bf16 out.
// ---------------------------------------------------------------------------
__device__ __forceinline__ void agg_row_fp8(const unsigned char* feat, int b, int e,
                                            int lane, const int* es,
                                            unsigned short* outrow) {
    int quad = lane >> 4, l = lane & 15;
    float acc[16] = {};
    for (int i = b + quad; i < e; i += 4) {
        int src = es[i];
        uint4 raw = *(const uint4*)(feat + (size_t)src * DIM + l * 16);
        float2v f;
        f = __builtin_amdgcn_cvt_pk_f32_fp8(raw.x, 0); acc[0]  += f.x; acc[1]  += f.y;
        f = __builtin_amdgcn_cvt_pk_f32_fp8(raw.x, 1); acc[2]  += f.x; acc[3]  += f.y;
        f = __builtin_amdgcn_cvt_pk_f32_fp8(raw.y, 0); acc[4]  += f.x; acc[5]  += f.y;
        f = __builtin_amdgcn_cvt_pk_f32_fp8(raw.y, 1); acc[6]  += f.x; acc[7]  += f.y;
        f = __builtin_amdgcn_cvt_pk_f32_fp8(raw.z, 0); acc[8]  += f.x; acc[9]  += f.y;
        f = __builtin_amdgcn_cvt_pk_f32_fp8(raw.z, 1); acc[10] += f.x; acc[11] += f.y;
        f = __builtin_amdgcn_cvt_pk_f32_fp8(raw.w, 0); acc[12] += f.x; acc[13] += f.y;
        f = __builtin_amdgcn_cvt_pk_f32_fp8(raw.w, 1); acc[14] += f.x; acc[15] += f.y;
    }
    #pragma unroll
    for (int j = 0; j < 16; ++j) {
        acc[j] += __shfl_xor(acc[j], 16, 64);
        acc[j] += __shfl_xor(acc[j], 32, 64);
    }
    if (quad == 0) {
        ushort8v o0, o1;
        #pragma unroll
        for (int j = 0; j < 8; ++j) { o0[j] = f2bf(acc[j]); o1[j] = f2bf(acc[8 + j]); }
        *(ushort8v*)(outrow + l * 16) = o0;
        *(ushort8v*)(outrow + l * 16 + 8) = o1;
    }
}

__global__ __launch_bounds__(256) void aggregate_l1_kernel(const unsigned char* __restrict__ xq,
                                                           const int* __restrict__ row_start,
                                                           const int* __restrict__ esorted,
                                                           unsigned short* __restrict__ aggbase) {
    int s = blockIdx.y;                            // slot 0..3 = rel {0,1,2,4}
    int srct = (s == 2) ? 1 : ((s == 3) ? 2 : 0);
    const unsigned char* feat = xq + (size_t)srct * NN * DIM;
    const int* rs = row_start + s * NP1;
    const int* es = esorted + s * NE;
    unsigned short* out = aggbase + (size_t)s * NN * DIM;
    int w = threadIdx.x >> 6, lane = threadIdx.x & 63;
    int row = blockIdx.x * 4 + w;
    if (row >= NN) return;
    agg_row_fp8(feat, rs[row], rs[row + 1], lane, es, out + (size_t)row * DIM);
}

__global__ __launch_bounds__(256) void aggregate_l2_kernel(const unsigned char* __restrict__ h0q,
                                                           const unsigned char* __restrict__ h1q,
                                                           const int* __restrict__ row_start,
                                                           const int* __restrict__ esorted,
                                                           unsigned short* __restrict__ aggbase) {
    int q = blockIdx.y;                 // 0: rel k0 (src h0) -> slot0; 1: rel k2 (src h1) -> slot2
    int slot = q ? 2 : 0;
    const unsigned char* feat = q ? h1q : h0q;
    const int* rs = row_start + slot * NP1;
    const int* es = esorted + slot * NE;
    unsigned short* out = aggbase + (size_t)slot * NN * DIM;
    int w = threadIdx.x >> 6, lane = threadIdx.x & 63;
    int row = blockIdx.x * 4 + w;
    if (row >= NN) return;
    agg_row_fp8(feat, rs[row], rs[row + 1], lane, es, out + (size_t)row * DIM);
}

// ---------------------------------------------------------------------------
// MFMA bf16 GEMM (m97 structure): 128x128 tile, BK=32, global_load_lds w=16.
// blockIdx.z selects one of up to 2 fused problems. Optional fp8 shadow out.
// ---------------------------------------------------------------------------
struct GemmArgs {
    const unsigned short* A0[2];
    const unsigned short* A1[2];
    const unsigned short* A2[2];
    const unsigned short* BT[2];
    const float* bias[2];
    unsigned short* Cb[2];   // bf16 out (or null)
    unsigned char* Cq[2];    // fp8 shadow out (or null)
    float* Cf[2];            // fp32 out (or null)
    int relu;
    int M;
};

__global__ __launch_bounds__(256) void gemm_mfma_lds_kernel(GemmArgs ga) {
    __shared__ unsigned short Atile[128 * 32];
    __shared__ unsigned short Btile[128 * 32];
    int z = blockIdx.z;
    const unsigned short* Asrc[3] = {ga.A0[z], ga.A1[z], ga.A2[z]};
    const unsigned short* BT = ga.BT[z];
    int M = ga.M;

    int tid = threadIdx.x;
    int wave = tid >> 6, lane = tid & 63;
    int wr = wave >> 1, wc = wave & 1;
    int row0 = blockIdx.x * 128;
    int col0 = blockIdx.y * 128;
    int q = lane >> 4, r = lane & 15;

    int idx0 = tid, idx1 = 256 + tid;
    int arow0 = idx0 >> 2, arow1 = idx1 >> 2;
    int acol0 = (idx0 & 3) * 8, acol1 = (idx1 & 3) * 8;
    int ra0 = row0 + arow0; if (ra0 > M - 1) ra0 = M - 1;
    int ra1 = row0 + arow1; if (ra1 > M - 1) ra1 = M - 1;
    size_t aoff0 = (size_t)ra0 * DIM + acol0;
    size_t aoff1 = (size_t)ra1 * DIM + acol1;
    size_t boff0 = (size_t)(col0 + arow0) * 768 + acol0;
    size_t boff1 = (size_t)(col0 + arow1) * 768 + acol1;
    unsigned short* ldsA0 = &Atile[(size_t)(tid & ~63) * 8];
    unsigned short* ldsA1 = &Atile[2048 + (size_t)(tid & ~63) * 8];
    unsigned short* ldsB0 = &Btile[(size_t)(tid & ~63) * 8];
    unsigned short* ldsB1 = &Btile[2048 + (size_t)(tid & ~63) * 8];

    float4v acc[4][4] = {};
    #pragma unroll 1
    for (int seg = 0; seg < 3; ++seg) {
        const unsigned short* Ap = Asrc[seg];
        #pragma unroll 1
        for (int kt = 0; kt < 8; ++kt) {
            int kl = kt * 32;
            int kb = seg * 256 + kl;
            __builtin_amdgcn_global_load_lds((gbl_vp*)(Ap + aoff0 + kl), (lds_vp*)ldsA0, 16, 0, 0);
            __builtin_amdgcn_global_load_lds((gbl_vp*)(Ap + aoff1 + kl), (lds_vp*)ldsA1, 16, 0, 0);
            __builtin_amdgcn_global_load_lds((gbl_vp*)(BT + boff0 + kb), (lds_vp*)ldsB0, 16, 0, 0);
            __builtin_amdgcn_global_load_lds((gbl_vp*)(BT + boff1 + kb), (lds_vp*)ldsB1, 16, 0, 0);
            __syncthreads();
            short8v a[4], b[4];
            #pragma unroll
            for (int i = 0; i < 4; ++i)
                a[i] = *(const short8v*)&Atile[(size_t)(wr * 64 + i * 16 + r) * 32 + q * 8];
            #pragma unroll
            for (int j = 0; j < 4; ++j)
                b[j] = *(const short8v*)&Btile[(size_t)(wc * 64 + j * 16 + r) * 32 + q * 8];
            #pragma unroll
            for (int i = 0; i < 4; ++i)
                #pragma unroll
                for (int j = 0; j < 4; ++j)
                    acc[i][j] = __builtin_amdgcn_mfma_f32_16x16x32_bf16(a[i], b[j], acc[i][j], 0, 0, 0);
            __syncthreads();
        }
    }

    // Epilogue. C/D layout: col = r, row = q*4 + e
    unsigned short* Cb = ga.Cb[z];
    unsigned char* Cq = ga.Cq[z];
    float* Cf = ga.Cf[z];
    int rowW0 = row0 + wr * 64;
    int colW0 = col0 + wc * 64;
    float bj[4];
    #pragma unroll
    for (int j = 0; j < 4; ++j) bj[j] = ga.bias[z][colW0 + j * 16 + r];
    #pragma unroll
    for (int i = 0; i < 4; ++i) {
        int rowb = rowW0 + i * 16 + q * 4;
        #pragma unroll
        for (int e = 0; e < 4; ++e) {
            int rowc = rowb + e;
            if (rowc < M) {
                #pragma unroll
                for (int j = 0; j < 4; ++j) {
                    int col = colW0 + j * 16 + r;
                    float v = acc[i][j][e] + bj[j];
                    if (ga.relu) v = fmaxf(v, 0.f);
                    if (Cb) {
                        Cb[(size_t)rowc * DIM + col] = f2bf(v);
                        if (Cq) Cq[(size_t)rowc * DIM + col] = f2fp8(v);
                    } else {
                        Cf[(size_t)rowc * DIM + col] = v;
                    }
                }
            }
        }
    }
}

// ---------------------------------------------------------------------------
// Loss
// ---------------------------------------------------------------------------
__global__ __launch_bounds__(256) void loss_rows_kernel(const float* __restrict__ logits,
                                                        const int* __restrict__ y,
                                                        float* __restrict__ nll) {
    int w = threadIdx.x >> 6, lane = threadIdx.x & 63;
    int row = blockIdx.x * 4 + w;
    if (row >= NN) return;
    float4 v = *(const float4*)(logits + (size_t)row * DIM + lane * 4);
    float m = fmaxf(fmaxf(v.x, v.y), fmaxf(v.z, v.w));
    #pragma unroll
    for (int off = 32; off; off >>= 1) m = fmaxf(m, __shfl_xor(m, off, 64));
    float s = __expf(v.x - m) + __expf(v.y - m) + __expf(v.z - m) + __expf(v.w - m);
    #pragma unroll
    for (int off = 32; off; off >>= 1) s += __shfl_xor(s, off, 64);
    float lse = m + __logf(s);
    int cls = y[row];
    int owner = cls >> 2;
    int sub = cls & 3;
    float pick = (sub & 2) ? ((sub & 1) ? v.w : v.z) : ((sub & 1) ? v.y : v.x);
    float ly = __shfl(pick, owner, 64);
    if (lane == 0) nll[row] = lse - ly;
}

__global__ __launch_bounds__(256) void reduce_mean_kernel(const float* __restrict__ nll,
                                                          float* __restrict__ out) {
    float s = 0.f;
    for (int i = threadIdx.x; i < NN; i += 256) s += nll[i];
    #pragma unroll
    for (int off = 32; off; off >>= 1) s += __shfl_xor(s, off, 64);
    __shared__ float ws_[4];
    int w = threadIdx.x >> 6, lane = threadIdx.x & 63;
    if (lane == 0) ws_[w] = s;
    __syncthreads();
    if (threadIdx.x == 0) out[0] = (ws_[0] + ws_[1] + ws_[2] + ws_[3]) / (float)NN;
}

// ---------------------------------------------------------------------------
extern "C" void kernel_launch(void* const* d_in, const int* in_sizes, int n_in,
                              void* d_out, int out_size, void* d_ws, size_t ws_size,
                              hipStream_t stream) {
    const float* x    = (const float*)d_in[0];
    const int*   edges= (const int*)d_in[1];
    const int*   y    = (const int*)d_in[2];
    const float* Wr1  = (const float*)d_in[3];
    const float* br1  = (const float*)d_in[4];
    const float* Wo1  = (const float*)d_in[5];
    const float* Wr2  = (const float*)d_in[6];
    const float* br2  = (const float*)d_in[7];
    const float* Wo2  = (const float*)d_in[8];
    float* out = (float*)d_out;

    char* ws = (char*)d_ws;
    size_t off = 0;
    auto alloc = [&](size_t bytes) {
        char* p = ws + off;
        off += (bytes + 511) & ~size_t(511);
        return p;
    };
    int*   bucket_counts = (int*)alloc(4 * NBKT * sizeof(int));
    int*   bucket_start  = (int*)alloc(4 * (NBKT + 1) * sizeof(int));
    int*   bucket_cursor = (int*)alloc(4 * NBKT * sizeof(int));
    uint2* pairs         = (uint2*)alloc(4 * (size_t)NE * sizeof(uint2));
    int*   rowstart      = (int*)alloc(4 * NP1 * sizeof(int));
    int*   esorted       = (int*)alloc(4 * (size_t)NE * sizeof(int));
    unsigned short* BT      = (unsigned short*)alloc(3 * 768 * (size_t)DIM * 2);
    float*          biascat = (float*)         alloc(3 * DIM * sizeof(float));
    unsigned short* xb      = (unsigned short*)alloc(2 * (size_t)NN * DIM * 2);
    unsigned char*  xq      = (unsigned char*) alloc(3 * (size_t)NN * DIM);
    unsigned short* agg     = (unsigned short*)alloc(4 * (size_t)NN * DIM * 2);
    unsigned short* h0      = (unsigned short*)alloc((size_t)NN * DIM * 2);
    unsigned short* h1      = (unsigned short*)alloc((size_t)NN * DIM * 2);
    unsigned char*  h0q     = (unsigned char*) alloc((size_t)NN * DIM);
    unsigned char*  h1q     = (unsigned char*) alloc((size_t)NN * DIM);
    float*          logits  = (float*)         alloc((size_t)NN * DIM * sizeof(float));
    float*          nll     = (float*)         alloc(NN * sizeof(float));
    (void)in_sizes; (void)n_in; (void)out_size; (void)ws_size;

    const size_t ND = (size_t)NN * DIM;

    // 1. Fused setup (zero bucket counts | x->bf16/fp8 | weight prep)
    setup_kernel<<<dim3(ZB_BLOCKS + CONV_BLOCKS + PREP_BLOCKS), 256, 0, stream>>>(
        x, Wr1, br1, Wo1, Wr2, br2, Wo2, bucket_counts, xb, xq, BT, biascat);

    // 2. Bucket sort: count -> scan -> bin -> per-bucket scatter (LDS atomics)
    binA_count_kernel<<<dim3(ABLK, 4), 256, 0, stream>>>(edges, bucket_counts);
    bucket_scan_kernel<<<dim3(1), 64, 0, stream>>>(bucket_counts, bucket_start, bucket_cursor);
    binA_scatter_kernel<<<dim3(ABLK, 4), 256, 0, stream>>>(edges, bucket_cursor, pairs);
    binB_kernel<<<dim3(NBKT, 4), 256, 0, stream>>>(pairs, bucket_start, rowstart, esorted);

    // 3. Layer-1 aggregation (4 relations, fp8 gather -> bf16 agg)
    aggregate_l1_kernel<<<dim3(NN / 4, 4), 256, 0, stream>>>(xq, rowstart, esorted, agg);

    // 4. Layer-1 MFMA GEMMs, both node types fused via blockIdx.z; h bf16 + fp8
    {
        GemmArgs ga;
        ga.A0[0] = agg + 0 * ND; ga.A1[0] = agg + 2 * ND; ga.A2[0] = xb + 0 * ND;
        ga.A0[1] = agg + 1 * ND; ga.A1[1] = agg + 3 * ND; ga.A2[1] = xb + 1 * ND;
        ga.BT[0] = BT + 0 * 768 * DIM; ga.BT[1] = BT + 1 * 768 * DIM;
        ga.bias[0] = biascat + 0 * DIM; ga.bias[1] = biascat + 1 * DIM;
        ga.Cb[0] = h0; ga.Cb[1] = h1;
        ga.Cq[0] = h0q; ga.Cq[1] = h1q;
        ga.Cf[0] = nullptr; ga.Cf[1] = nullptr;
        ga.relu = 1; ga.M = NN;
        gemm_mfma_lds_kernel<<<dim3((NN + 127) / 128, 2, 2), 256, 0, stream>>>(ga);
    }

    // 5. Layer-2 aggregation (fp8 gather from h0q/h1q)
    aggregate_l2_kernel<<<dim3(NN / 4, 2), 256, 0, stream>>>(h0q, h1q, rowstart, esorted, agg);

    // 6. Layer-2 MFMA GEMM (t=0), fp32 logits out
    {
        GemmArgs ga;
        ga.A0[0] = agg + 0 * ND; ga.A1[0] = agg + 2 * ND; ga.A2[0] = h0;
        ga.A0[1] = ga.A0[0]; ga.A1[1] = ga.A1[0]; ga.A2[1] = ga.A2[0];
        ga.BT[0] = BT + 2 * 768 * DIM; ga.BT[1] = ga.BT[0];
        ga.bias[0] = biascat + 2 * DIM; ga.bias[1] = ga.bias[0];
        ga.Cb[0] = nullptr; ga.Cb[1] = nullptr;
        ga.Cq[0] = nullptr; ga.Cq[1] = nullptr;
        ga.Cf[0] = logits; ga.Cf[1] = logits;
        ga.relu = 0; ga.M = NN;
        gemm_mfma_lds_kernel<<<dim3((NN + 127) / 128, 2, 1), 256, 0, stream>>>(ga);
    }

    // 7. Loss
    loss_rows_kernel<<<dim3(NN / 4), 256, 0, stream>>>(logits, y, nll);
    reduce_mean_kernel<<<dim3(1), 256, 0, stream>>>(nll, out);
}